// Round 10
// baseline (1482.890 us; speedup 1.0000x reference)
//
#include <hip/hip_runtime.h>

#define NROWS 50000
#define DIM   256
#define SHOPS 6
#define ROUNDS 4
#define EPSV  1e-5f
#define ND ((size_t)NROWS * DIM)
#define NB  196                              // ceil(NROWS/256)

typedef _Float16 f16x8 __attribute__((ext_vector_type(8)));
typedef _Float16 f16x4 __attribute__((ext_vector_type(4)));
typedef float    f32x4 __attribute__((ext_vector_type(4)));

#define GLDS16(GP, LP) \
    __builtin_amdgcn_global_load_lds((const __attribute__((address_space(1))) unsigned*)(GP), \
                                     (__attribute__((address_space(3))) unsigned*)(LP), 16, 0, 0)

__device__ __forceinline__ int imin(int a, int b) { return a < b ? a : b; }

// ---------------------------------------------------------------------------
// Pipelined fp16 MFMA GEMM with optional A-side row gather + compacted output.
// C[z] = rows of (A_gathered @ W[wslot(z)]^T); wslot(z) = z==0 ? s0 : s1+z.
// Slot z's segment = sbase + z; seg < 0 -> identity (all NROWS rows live),
// else A rows come from LIVE[seg*N + r'], output rows r' < Ecnt[seg]
// (compacted); blocks with bm0 >= Ecnt exit immediately.
// r8 structure: XCD-chunked bijective swizzle, 3-buf counted-vmcnt pipeline
// (BK=32, 8 k-steps), 64B-row XOR LDS swizzle, LDS-transposed coalesced
// epilogue ([128][136], 16B stores).
// ---------------------------------------------------------------------------
__global__ __launch_bounds__(256)
void gemm_p(const _Float16* __restrict__ A, const _Float16* __restrict__ WH,
            int s0, int s1, int nz, _Float16* __restrict__ C16, int nwg,
            const int* __restrict__ LIVE, const int* __restrict__ Ecnt,
            int sbase)
{
    __shared__ _Float16 lds[3][8192];        // 3 x (A 8KB + W 8KB) = 48KB
    char* ldsb = (char*)lds;

    // bijective XCD chunking (m204): consecutive g on same XCD; g is bx-major.
    const int bid = blockIdx.x;
    const int q   = nwg >> 3, r = nwg & 7;
    const int xcd = bid & 7,  ii = bid >> 3;
    const int g   = (xcd < r) ? xcd * (q + 1) + ii
                              : r * (q + 1) + (xcd - r) * q + ii;
    const int bx  = g / (2 * nz);
    const int sub = g - bx * 2 * nz;
    const int by  = sub & 1;
    const size_t z = sub >> 1;

    const int seg = sbase + (int)z;
    const int En  = (seg >= 0) ? Ecnt[seg] : NROWS;
    const int bm0 = bx * 128;
    if (bm0 >= En) return;                   // dead block (compacted slot)
    const int* lvp = (seg >= 0) ? LIVE + (size_t)seg * NROWS : nullptr;

    const int tid = threadIdx.x;
    const int l   = tid & 63;
    const int w   = tid >> 6;
    const int wm  = w & 1;
    const int wn  = w >> 1;
    const int bn0 = by * 128;
    const int lr  = l & 15;
    const int sl  = l >> 4;                  // logical 16B k-slot 0..3

    const int wslot = (z == 0) ? s0 : s1 + (int)z;
    const char* Ab = (const char*)A;
    const char* Wb = (const char*)(WH + (size_t)wslot * (DIM * DIM));

    // per-thread staging geometry (constant across k-steps)
    int arow[2], slog[2], wrow[2];
    #pragma unroll
    for (int qq = 0; qq < 2; ++qq) {
        const int c   = (w * 2 + qq) * 64 + l;       // 16B chunk 0..511
        const int row = c >> 2;                      // 0..127
        slog[qq] = (c & 3) ^ ((row >> 1) & 3);       // inverse-swizzled slot
        const int cl = imin(bm0 + row, En - 1);
        arow[qq] = lvp ? lvp[cl] : cl;               // gathered A row
        wrow[qq] = bn0 + row;
    }

    f32x4 acc[4][4];
    #pragma unroll
    for (int mt = 0; mt < 4; ++mt)
        #pragma unroll
        for (int nt = 0; nt < 4; ++nt)
            acc[mt][nt] = (f32x4){0.f, 0.f, 0.f, 0.f};

    auto stage = [&](int step, int buf) {
        const int kt64 = step * 64;
        char* base = ldsb + buf * 16384;
        #pragma unroll
        for (int qq = 0; qq < 2; ++qq) {
            GLDS16(Ab + (size_t)arow[qq] * 512 + kt64 + slog[qq] * 16,
                   base + (w * 2 + qq) * 1024);
            GLDS16(Wb + (size_t)wrow[qq] * 512 + kt64 + slog[qq] * 16,
                   base + 8192 + (w * 2 + qq) * 1024);
        }
    };

    auto compute = [&](int buf) {
        const char* base = ldsb + buf * 16384;
        f16x8 af[4], bf[4];
        #pragma unroll
        for (int mt = 0; mt < 4; ++mt) {
            const int row = wm * 64 + mt * 16 + lr;
            af[mt] = *(const f16x8*)(base + row * 64 + ((sl ^ ((row >> 1) & 3)) << 4));
        }
        #pragma unroll
        for (int nt = 0; nt < 4; ++nt) {
            const int row = wn * 64 + nt * 16 + lr;
            bf[nt] = *(const f16x8*)(base + 8192 + row * 64 + ((sl ^ ((row >> 1) & 3)) << 4));
        }
        #pragma unroll
        for (int mt = 0; mt < 4; ++mt)
            #pragma unroll
            for (int nt = 0; nt < 4; ++nt)
                acc[mt][nt] = __builtin_amdgcn_mfma_f32_16x16x32_f16(
                    af[mt], bf[nt], acc[mt][nt], 0, 0, 0);
    };

    stage(0, 0);
    stage(1, 1);

    #pragma unroll
    for (int t = 0; t < 7; ++t) {
        asm volatile("s_waitcnt vmcnt(4)" ::: "memory");   // stage(t) landed
        __builtin_amdgcn_s_barrier();
        __builtin_amdgcn_sched_barrier(0);
        if (t < 6) stage(t + 2, (t + 2) % 3);              // stays in flight
        compute(t % 3);
    }
    asm volatile("s_waitcnt vmcnt(0)" ::: "memory");
    __builtin_amdgcn_s_barrier();
    __builtin_amdgcn_sched_barrier(0);
    compute(7 % 3);

    // ---- epilogue: transpose through LDS, 16B coalesced stores ----
    __syncthreads();
    _Float16* et = (_Float16*)ldsb;           // [128][136] fp16 = 34816 B
    #pragma unroll
    for (int mt = 0; mt < 4; ++mt)
        #pragma unroll
        for (int nt = 0; nt < 4; ++nt)
            #pragma unroll
            for (int j = 0; j < 4; ++j) {
                const int row = wm * 64 + mt * 16 + sl * 4 + j;   // 0..127
                const int col = wn * 64 + nt * 16 + lr;           // 0..127
                et[row * 136 + col] = (_Float16)acc[mt][nt][j];
            }
    __syncthreads();
    const size_t zoff = z * ND;
    #pragma unroll
    for (int qq = 0; qq < 8; ++qq) {
        const int c   = qq * 256 + tid;       // 0..2047 16B-chunk id
        const int row = c >> 4;               // 0..127
        const int cc  = (c & 15) * 8;         // f16 col 0..120
        const int orow = bm0 + row;
        if (orow < En) {
            const f16x8 v = *(const f16x8*)(et + row * 136 + cc);
            *(f16x8*)(C16 + zoff + (size_t)orow * DIM + bn0 + cc) = v;
        }
    }
}

// ---------------------------------------------------------------------------
__global__ __launch_bounds__(256)
void convert_w(const float* __restrict__ Wctr, const float* __restrict__ Wctr2,
               const float* __restrict__ Wpre, const float* __restrict__ Wsuc,
               _Float16* __restrict__ WH)
{
    const size_t i4 = (size_t)blockIdx.x * 256 + threadIdx.x;
    const size_t NT = (size_t)56 * DIM * DIM / 4;
    if (i4 >= NT) return;
    const size_t e = i4 * 4;
    const int slot = (int)(e >> 16);
    const int off  = (int)(e & 65535);
    const float* src;
    if (slot < 48) {
        const int r = slot / 12, s = slot % 12, k = s >> 1, dir = s & 1;
        src = (dir ? Wsuc : Wpre) + (((size_t)r * SHOPS + k) << 16) + off;
    } else if (slot < 52) {
        src = Wctr + ((size_t)(slot - 48) << 16) + off;
    } else {
        src = Wctr2 + ((size_t)(slot - 52) << 16) + off;
    }
    const float4 v = *(const float4*)src;
    f16x4 h;
    h[0] = (_Float16)v.x; h[1] = (_Float16)v.y;
    h[2] = (_Float16)v.z; h[3] = (_Float16)v.w;
    *(f16x4*)(WH + e) = h;
}

// Xh = fp16(lane). fp32 X is written only in the final round's gn1.
__global__ __launch_bounds__(256)
void init_x(const float* __restrict__ lane, _Float16* __restrict__ Xh)
{
    const size_t i4 = (size_t)blockIdx.x * 256 + threadIdx.x;
    if (i4 >= ND / 4) return;
    const float4 v = *(const float4*)(lane + i4 * 4);
    f16x4 h;
    h[0] = (_Float16)v.x; h[1] = (_Float16)v.y;
    h[2] = (_Float16)v.z; h[3] = (_Float16)v.w;
    *(f16x4*)(Xh + i4 * 4) = h;
}

// x = relu(gn(y)*w+b + res[fp16]) -> Xh fp16 (+ X fp32 iff WRITEX)
template<int WRITEX>
__global__ __launch_bounds__(256)
void gn1_kernel(const _Float16* __restrict__ inh, const float* __restrict__ w,
                const float* __restrict__ b, const _Float16* __restrict__ resh,
                float* __restrict__ X, _Float16* __restrict__ Xh)
{
    const int lane = threadIdx.x & 63;
    const int wv   = threadIdx.x >> 6;
    const int row  = blockIdx.x * 4 + wv;
    if (row >= NROWS) return;
    const size_t rowoff = (size_t)row * DIM + lane * 4;

    const f16x4 hv = *(const f16x4*)(inh + rowoff);
    float4 v;
    v.x = (float)hv[0]; v.y = (float)hv[1]; v.z = (float)hv[2]; v.w = (float)hv[3];
    float s  = v.x + v.y + v.z + v.w;
    float ss = v.x * v.x + v.y * v.y + v.z * v.z + v.w * v.w;
    #pragma unroll
    for (int off = 32; off >= 1; off >>= 1) {
        s  += __shfl_xor(s, off);
        ss += __shfl_xor(ss, off);
    }
    const float m   = s * (1.0f / DIM);
    const float var = ss * (1.0f / DIM) - m * m;
    const float inv = rsqrtf(var + EPSV);

    const float4 wv4 = *(const float4*)(w + lane * 4);
    const float4 bv4 = *(const float4*)(b + lane * 4);
    const f16x4  r4  = *(const f16x4*)(resh + rowoff);
    float4 o;
    o.x = fmaxf((v.x - m) * inv * wv4.x + bv4.x + (float)r4[0], 0.f);
    o.y = fmaxf((v.y - m) * inv * wv4.y + bv4.y + (float)r4[1], 0.f);
    o.z = fmaxf((v.z - m) * inv * wv4.z + bv4.z + (float)r4[2], 0.f);
    o.w = fmaxf((v.w - m) * inv * wv4.w + bv4.w + (float)r4[3], 0.f);
    if (WRITEX)
        *(float4*)(X + rowoff) = o;
    f16x4 oh;
    oh[0] = (_Float16)o.x; oh[1] = (_Float16)o.y;
    oh[2] = (_Float16)o.z; oh[3] = (_Float16)o.w;
    *(f16x4*)(Xh + rowoff) = oh;
}

// ---------------------------------------------------------------------------
// Prep: live-row analysis per segment + CSR inversion (once per launch)
// ---------------------------------------------------------------------------
__global__ __launch_bounds__(256)
void markk(const int* __restrict__ nhp, const int* __restrict__ nhs,
           int* __restrict__ mark)
{
    const int i = blockIdx.x * 256 + threadIdx.x;
    if (i >= NROWS) return;
    const int s = blockIdx.y;
    const int k = s >> 1, dir = s & 1;
    const int* gp = (dir ? nhs : nhp) + k * NROWS;
    mark[(size_t)s * NROWS + gp[i]] = 1;     // races write same value: benign
}

__global__ __launch_bounds__(256)
void mscan1(const int* __restrict__ mark, int* __restrict__ mrank,
            int* __restrict__ msum)
{
    __shared__ int wsum[4];
    const int s = blockIdx.y;
    const int tid = threadIdx.x, lane = tid & 63, wv = tid >> 6;
    const int i = blockIdx.x * 256 + tid;
    const int c = (i < NROWS) ? mark[(size_t)s * NROWS + i] : 0;
    int v = c;
    #pragma unroll
    for (int off = 1; off < 64; off <<= 1) {
        const int t = __shfl_up(v, off);
        if (lane >= off) v += t;
    }
    if (lane == 63) wsum[wv] = v;
    __syncthreads();
    int add = 0;
    for (int w = 0; w < wv; ++w) add += wsum[w];
    if (i < NROWS) mrank[(size_t)s * NROWS + i] = add + v - c;
    if (tid == 255) msum[s * 256 + blockIdx.x] = wsum[0] + wsum[1] + wsum[2] + wsum[3];
}

__global__ __launch_bounds__(256)
void mscan2(const int* __restrict__ msum, int* __restrict__ mbpre,
            int* __restrict__ Ecnt)
{
    __shared__ int wsum[4];
    const int s = blockIdx.x;
    const int tid = threadIdx.x, lane = tid & 63, wv = tid >> 6;
    const int c = (tid < NB) ? msum[s * 256 + tid] : 0;
    int v = c;
    #pragma unroll
    for (int off = 1; off < 64; off <<= 1) {
        const int t = __shfl_up(v, off);
        if (lane >= off) v += t;
    }
    if (lane == 63) wsum[wv] = v;
    __syncthreads();
    int add = 0;
    for (int w = 0; w < wv; ++w) add += wsum[w];
    if (tid < NB) mbpre[s * 256 + tid] = add + v - c;
    if (tid == 0) Ecnt[s] = wsum[0] + wsum[1] + wsum[2] + wsum[3];
}

__global__ __launch_bounds__(256)
void mscan3(const int* __restrict__ mark, int* __restrict__ mrank,
            const int* __restrict__ mbpre, int* __restrict__ live)
{
    const int i = blockIdx.x * 256 + threadIdx.x;
    if (i >= NROWS) return;
    const int s = blockIdx.y;
    const size_t o = (size_t)s * NROWS + i;
    const int rk = mrank[o] + mbpre[s * 256 + blockIdx.x];
    mrank[o] = rk;
    if (mark[o]) live[(size_t)s * NROWS + rk] = i;
}

__global__ __launch_bounds__(256)
void count_kernel(const int* __restrict__ pidx, const int* __restrict__ sidx,
                  int* __restrict__ counts)
{
    const int i = blockIdx.x * 256 + threadIdx.x;
    if (i >= NROWS) return;
    const int s = blockIdx.y;
    const int k = s >> 1, dir = s & 1;
    const int* scp = (dir ? pidx : sidx) + k * NROWS;
    atomicAdd(&counts[scp[i]], 1);
}

__global__ __launch_bounds__(256)
void scan1_kernel(const int* __restrict__ counts, int* __restrict__ offs,
                  int* __restrict__ bsum)
{
    __shared__ int wsum[4];
    const int tid = threadIdx.x, lane = tid & 63, wv = tid >> 6;
    const int i = blockIdx.x * 256 + tid;
    const int c = (i < NROWS) ? counts[i] : 0;
    int v = c;
    #pragma unroll
    for (int off = 1; off < 64; off <<= 1) {
        const int t = __shfl_up(v, off);
        if (lane >= off) v += t;
    }
    if (lane == 63) wsum[wv] = v;
    __syncthreads();
    int add = 0;
    for (int w = 0; w < wv; ++w) add += wsum[w];
    if (i < NROWS) offs[i] = add + v - c;
    if (tid == 255) bsum[blockIdx.x] = wsum[0] + wsum[1] + wsum[2] + wsum[3];
}

__global__ __launch_bounds__(256)
void scan2_kernel(const int* __restrict__ bsum, int* __restrict__ bpre)
{
    __shared__ int wsum[4];
    const int tid = threadIdx.x, lane = tid & 63, wv = tid >> 6;
    const int c = (tid < NB) ? bsum[tid] : 0;
    int v = c;
    #pragma unroll
    for (int off = 1; off < 64; off <<= 1) {
        const int t = __shfl_up(v, off);
        if (lane >= off) v += t;
    }
    if (lane == 63) wsum[wv] = v;
    __syncthreads();
    int add = 0;
    for (int w = 0; w < wv; ++w) add += wsum[w];
    if (tid < NB) bpre[tid] = add + v - c;
}

__global__ __launch_bounds__(256)
void scan3_kernel(int* __restrict__ offs, const int* __restrict__ bpre,
                  int* __restrict__ cursor)
{
    const int i = blockIdx.x * 256 + threadIdx.x;
    if (i < NROWS) {
        const int v = offs[i] + bpre[blockIdx.x];
        offs[i] = v;
        cursor[i] = v;
    }
    if (i == 0) offs[NROWS] = 12 * NROWS;
}

// entries store (seg << 16) | rank-in-compacted-Y
__global__ __launch_bounds__(256)
void fill_kernel(const int* __restrict__ pidx, const int* __restrict__ sidx,
                 const int* __restrict__ nhp, const int* __restrict__ nhs,
                 const int* __restrict__ mrank,
                 int* __restrict__ cursor, int* __restrict__ entries)
{
    const int i = blockIdx.x * 256 + threadIdx.x;
    if (i >= NROWS) return;
    const int s = blockIdx.y;
    const int k = s >> 1, dir = s & 1;
    const int* scp = (dir ? pidx : sidx) + k * NROWS;
    const int* gp  = (dir ? nhs  : nhp)  + k * NROWS;
    const int pos = atomicAdd(&cursor[scp[i]], 1);
    entries[pos] = (s << 16) | mrank[(size_t)s * NROWS + gp[i]];
}

// ---------------------------------------------------------------------------
// combine: acc = (FIRST ? YC[r] : TEMP16[r]) + sum of compacted-Y rows for
// entries with seg in [c0, c0+nch). LAST: fused GN+ReLU -> Hh; else -> TEMP16.
// ---------------------------------------------------------------------------
template<int FIRST, int LAST>
__global__ __launch_bounds__(256)
void combine_f16(const _Float16* __restrict__ YC, _Float16* __restrict__ TEMP16,
                 const _Float16* __restrict__ YB,
                 const int* __restrict__ offsets, const int* __restrict__ entries,
                 int c0, int nch,
                 const float* __restrict__ gw, const float* __restrict__ gb,
                 _Float16* __restrict__ Hh)
{
    const int lane = threadIdx.x & 63;
    const int wv   = threadIdx.x >> 6;
    const int r    = blockIdx.x * 4 + wv;
    if (r >= NROWS) return;
    const size_t rowoff = (size_t)r * DIM + lane * 4;

    const f16x4 iv = FIRST ? *(const f16x4*)(YC + rowoff)
                           : *(const f16x4*)(TEMP16 + rowoff);
    float4 acc;
    acc.x = (float)iv[0]; acc.y = (float)iv[1];
    acc.z = (float)iv[2]; acc.w = (float)iv[3];

    const int e0 = offsets[r], e1 = offsets[r + 1];
    for (int e = e0; e < e1; ++e) {
        const int ent = entries[e];
        const int s = ent >> 16;
        if ((unsigned)(s - c0) < (unsigned)nch) {
            const f16x4 yv = *(const f16x4*)(YB + (size_t)(s - c0) * ND
                                             + (size_t)(ent & 0xFFFF) * DIM + lane * 4);
            acc.x += (float)yv[0]; acc.y += (float)yv[1];
            acc.z += (float)yv[2]; acc.w += (float)yv[3];
        }
    }

    if (LAST) {
        float s  = acc.x + acc.y + acc.z + acc.w;
        float ss = acc.x * acc.x + acc.y * acc.y + acc.z * acc.z + acc.w * acc.w;
        #pragma unroll
        for (int off = 32; off >= 1; off >>= 1) {
            s  += __shfl_xor(s, off);
            ss += __shfl_xor(ss, off);
        }
        const float m   = s * (1.0f / DIM);
        const float var = ss * (1.0f / DIM) - m * m;
        const float inv = rsqrtf(var + EPSV);
        const float4 wv4 = *(const float4*)(gw + lane * 4);
        const float4 bv4 = *(const float4*)(gb + lane * 4);
        f16x4 o;
        o[0] = (_Float16)fmaxf((acc.x - m) * inv * wv4.x + bv4.x, 0.f);
        o[1] = (_Float16)fmaxf((acc.y - m) * inv * wv4.y + bv4.y, 0.f);
        o[2] = (_Float16)fmaxf((acc.z - m) * inv * wv4.z + bv4.z, 0.f);
        o[3] = (_Float16)fmaxf((acc.w - m) * inv * wv4.w + bv4.w, 0.f);
        *(f16x4*)(Hh + rowoff) = o;
    } else {
        f16x4 o;
        o[0] = (_Float16)acc.x; o[1] = (_Float16)acc.y;
        o[2] = (_Float16)acc.z; o[3] = (_Float16)acc.w;
        *(f16x4*)(TEMP16 + rowoff) = o;
    }
}

// ---------------------------------------------------------------------------
extern "C" void kernel_launch(void* const* d_in, const int* in_sizes, int n_in,
                              void* d_out, int out_size, void* d_ws, size_t ws_size,
                              hipStream_t stream)
{
    const float* lane   = (const float*)d_in[0];
    const float* W_ctr  = (const float*)d_in[1];
    const float* norm_w = (const float*)d_in[2];
    const float* norm_b = (const float*)d_in[3];
    const float* W_ctr2 = (const float*)d_in[4];
    const float* c2w    = (const float*)d_in[5];
    const float* c2b    = (const float*)d_in[6];
    const float* W_pre  = (const float*)d_in[7];
    const float* W_suc  = (const float*)d_in[8];
    const int*   pidx   = (const int*)d_in[9];
    const int*   sidx   = (const int*)d_in[10];
    const int*   nhp    = (const int*)d_in[11];
    const int*   nhs    = (const int*)d_in[12];

    float* X = (float*)d_out;

    // ---- workspace layout (YC must immediately precede YBUF) ----
    char* p = (char*)d_ws;
    int* counts  = (int*)p; p += (size_t)NROWS * 4;
    int* offsets = (int*)p; p += (size_t)(NROWS + 4) * 4;
    int* cursor  = (int*)p; p += (size_t)NROWS * 4;
    int* bsum    = (int*)p; p += 256 * 4;
    int* bpre    = (int*)p; p += 256 * 4;
    int* msum    = (int*)p; p += 12 * 256 * 4;
    int* mbpre   = (int*)p; p += 12 * 256 * 4;
    int* Ecnt    = (int*)p; p += 16 * 4;
    int* entries = (int*)p; p += (size_t)12 * NROWS * 4;
    int* LIVE    = (int*)p; p += (size_t)12 * NROWS * 4;
    p = (char*)(((uintptr_t)p + 15) & ~(uintptr_t)15);
    _Float16* Xh   = (_Float16*)p; p += ND * 2;
    _Float16* Hh   = (_Float16*)p; p += ND * 2;
    _Float16* T16  = (_Float16*)p; p += ND * 2;
    _Float16* WH   = (_Float16*)p; p += (size_t)56 * DIM * DIM * 2;
    p = (char*)(((uintptr_t)p + 15) & ~(uintptr_t)15);
    _Float16* YC   = (_Float16*)p; p += ND * 2;
    _Float16* YBUF = (_Float16*)p;            // contiguous after YC

    // prep-only arrays aliased into YBUF (clobbered later by GEMM writes,
    // but used strictly before the first GEMM each launch)
    int* mark  = (int*)YBUF;                  // 12N ints = 2.4MB
    int* mrank = mark + (size_t)12 * NROWS;   // 12N ints = 2.4MB

    const size_t used = (size_t)(p - (char*)d_ws);
    int nslot = (int)((ws_size - used) / (ND * 2));
    if (nslot < 1) nslot = 1;
    int CH = nslot > 12 ? 12 : nslot;
    const int nchunks = (12 + CH - 1) / CH;
    CH = (12 + nchunks - 1) / nchunks;
    _Float16* Y2 = YBUF;                      // ctr2 output reuses slot 0

    const dim3 blk(256);
    const int  gnBlocks = (NROWS + 3) / 4;
    const int  cwBlocks = (int)(((size_t)56 * DIM * DIM / 4 + 255) / 256);
    const int  ixBlocks = (int)((ND / 4 + 255) / 256);

    // one-time prep
    convert_w<<<cwBlocks, blk, 0, stream>>>(W_ctr, W_ctr2, W_pre, W_suc, WH);
    init_x<<<ixBlocks, blk, 0, stream>>>(lane, Xh);
    hipMemsetAsync(counts, 0, NROWS * sizeof(int), stream);
    hipMemsetAsync(mark, 0, (size_t)12 * NROWS * sizeof(int), stream);
    markk<<<dim3(NB, 12), blk, 0, stream>>>(nhp, nhs, mark);
    mscan1<<<dim3(NB, 12), blk, 0, stream>>>(mark, mrank, msum);
    mscan2<<<12, blk, 0, stream>>>(msum, mbpre, Ecnt);
    mscan3<<<dim3(NB, 12), blk, 0, stream>>>(mark, mrank, mbpre, LIVE);
    count_kernel<<<dim3(NB, 12), blk, 0, stream>>>(pidx, sidx, counts);
    scan1_kernel<<<NB, blk, 0, stream>>>(counts, offsets, bsum);
    scan2_kernel<<<1, blk, 0, stream>>>(bsum, bpre);
    scan3_kernel<<<NB, blk, 0, stream>>>(offsets, bpre, cursor);
    fill_kernel<<<dim3(NB, 12), blk, 0, stream>>>(pidx, sidx, nhp, nhs, mrank,
                                                  cursor, entries);

    for (int i = 0; i < ROUNDS; ++i) {
        // chunked msg GEMMs; first chunk also carries the ctr GEMM as z=0
        for (int c0 = 0; c0 < 12; c0 += CH) {
            const int nz  = (12 - c0 < CH) ? (12 - c0) : CH;
            const bool first = (c0 == 0);
            const bool last  = (c0 + nz >= 12);
            if (first) {
                // z=0 -> ctr (identity) -> YC; z=1..nz -> seg z-1 (compacted)
                const int nwg = 391 * 2 * (nz + 1);
                gemm_p<<<dim3(nwg), blk, 0, stream>>>(Xh, WH, 48 + i,
                    i * 12 + c0 - 1, nz + 1, YC, nwg, LIVE, Ecnt, c0 - 1);
            } else {
                const int nwg = 391 * 2 * nz;
                gemm_p<<<dim3(nwg), blk, 0, stream>>>(Xh, WH, i * 12 + c0,
                    i * 12 + c0, nz, YBUF, nwg, LIVE, Ecnt, c0);
            }
            if (first && last)
                combine_f16<1, 1><<<gnBlocks, blk, 0, stream>>>(YC, T16, YBUF,
                    offsets, entries, c0, nz, norm_w + i * DIM, norm_b + i * DIM, Hh);
            else if (first)
                combine_f16<1, 0><<<gnBlocks, blk, 0, stream>>>(YC, T16, YBUF,
                    offsets, entries, c0, nz, norm_w + i * DIM, norm_b + i * DIM, Hh);
            else if (last)
                combine_f16<0, 1><<<gnBlocks, blk, 0, stream>>>(YC, T16, YBUF,
                    offsets, entries, c0, nz, norm_w + i * DIM, norm_b + i * DIM, Hh);
            else
                combine_f16<0, 0><<<gnBlocks, blk, 0, stream>>>(YC, T16, YBUF,
                    offsets, entries, c0, nz, norm_w + i * DIM, norm_b + i * DIM, Hh);
        }
        // y = h @ W_ctr2[i].T (identity rows)
        {
            const int nwg = 391 * 2;
            gemm_p<<<dim3(nwg), blk, 0, stream>>>(Hh, WH, 52 + i, 52 + i, 1,
                                                  Y2, nwg, LIVE, Ecnt, -1000);
        }
        // x = relu(gn(y) + x); fp32 X written only in the final round
        if (i == ROUNDS - 1)
            gn1_kernel<1><<<gnBlocks, blk, 0, stream>>>(Y2, c2w + i * DIM,
                                                        c2b + i * DIM, Xh, X, Xh);
        else
            gn1_kernel<0><<<gnBlocks, blk, 0, stream>>>(Y2, c2w + i * DIM,
                                                        c2b + i * DIM, Xh, X, Xh);
    }
}

// Round 11
// 1308.478 us; speedup vs baseline: 1.1333x; 1.1333x over previous
//
#include <hip/hip_runtime.h>

#define NROWS 50000
#define DIM   256
#define SHOPS 6
#define ROUNDS 4
#define EPSV  1e-5f
#define ND ((size_t)NROWS * DIM)
#define NB  196                              // ceil(NROWS/256)

typedef _Float16 f16x8 __attribute__((ext_vector_type(8)));
typedef _Float16 f16x4 __attribute__((ext_vector_type(4)));
typedef float    f32x4 __attribute__((ext_vector_type(4)));

#define GLDS16(GP, LP) \
    __builtin_amdgcn_global_load_lds((const __attribute__((address_space(1))) unsigned*)(GP), \
                                     (__attribute__((address_space(3))) unsigned*)(LP), 16, 0, 0)

__device__ __forceinline__ int imin(int a, int b) { return a < b ? a : b; }

// ---------------------------------------------------------------------------
// Pipelined fp16 MFMA GEMM, A-side row gather + compacted output (r10) with
// PANEL-SPREADING FIX: within an XCD's contiguous g range, the panel index is
// bx = jj*8 + xp (inverse m204 over 391 panels), so each XCD gets panels
// strided by 8 -> compaction's dead tail (bx >= ceil(En/128)) and the Y
// writes distribute evenly over all 8 XCDs. z still varies fastest within an
// XCD -> X-row L2 locality preserved.
// ---------------------------------------------------------------------------
__global__ __launch_bounds__(256)
void gemm_p(const _Float16* __restrict__ A, const _Float16* __restrict__ WH,
            int s0, int s1, int nz, _Float16* __restrict__ C16, int nwg,
            const int* __restrict__ LIVE, const int* __restrict__ Ecnt,
            int sbase)
{
    __shared__ _Float16 lds[3][8192];        // 3 x (A 8KB + W 8KB) = 48KB
    char* ldsb = (char*)lds;

    // bijective XCD chunking (m204): consecutive g on same XCD
    const int bid = blockIdx.x;
    const int q   = nwg >> 3, r = nwg & 7;
    const int xcd = bid & 7,  ii = bid >> 3;
    const int g   = (xcd < r) ? xcd * (q + 1) + ii
                              : r * (q + 1) + (xcd - r) * q + ii;
    const int j   = g / (2 * nz);            // XCD-contiguous panel position
    const int sub = g - j * 2 * nz;
    const int by  = sub & 1;
    const size_t z = sub >> 1;

    // unchunk j -> panel (391 = 8*48 + 7): XCD's j-range -> panels mod-8 spread
    int xp, jj;
    if (j < 7 * 49) { xp = j / 49; jj = j % 49; }
    else            { const int t = j - 7 * 49; xp = 7; jj = t; }
    const int bx = jj * 8 + xp;

    const int seg = sbase + (int)z;
    const int En  = (seg >= 0) ? Ecnt[seg] : NROWS;
    const int bm0 = bx * 128;
    if (bm0 >= En) return;                   // dead block (compacted slot)
    const int* lvp = (seg >= 0) ? LIVE + (size_t)seg * NROWS : nullptr;

    const int tid = threadIdx.x;
    const int l   = tid & 63;
    const int w   = tid >> 6;
    const int wm  = w & 1;
    const int wn  = w >> 1;
    const int bn0 = by * 128;
    const int lr  = l & 15;
    const int sl  = l >> 4;                  // logical 16B k-slot 0..3

    const int wslot = (z == 0) ? s0 : s1 + (int)z;
    const char* Ab = (const char*)A;
    const char* Wb = (const char*)(WH + (size_t)wslot * (DIM * DIM));

    // per-thread staging geometry (constant across k-steps)
    int arow[2], slog[2], wrow[2];
    #pragma unroll
    for (int qq = 0; qq < 2; ++qq) {
        const int c   = (w * 2 + qq) * 64 + l;       // 16B chunk 0..511
        const int row = c >> 2;                      // 0..127
        slog[qq] = (c & 3) ^ ((row >> 1) & 3);       // inverse-swizzled slot
        const int cl = imin(bm0 + row, En - 1);
        arow[qq] = lvp ? lvp[cl] : cl;               // gathered A row
        wrow[qq] = bn0 + row;
    }

    f32x4 acc[4][4];
    #pragma unroll
    for (int mt = 0; mt < 4; ++mt)
        #pragma unroll
        for (int nt = 0; nt < 4; ++nt)
            acc[mt][nt] = (f32x4){0.f, 0.f, 0.f, 0.f};

    auto stage = [&](int step, int buf) {
        const int kt64 = step * 64;
        char* base = ldsb + buf * 16384;
        #pragma unroll
        for (int qq = 0; qq < 2; ++qq) {
            GLDS16(Ab + (size_t)arow[qq] * 512 + kt64 + slog[qq] * 16,
                   base + (w * 2 + qq) * 1024);
            GLDS16(Wb + (size_t)wrow[qq] * 512 + kt64 + slog[qq] * 16,
                   base + 8192 + (w * 2 + qq) * 1024);
        }
    };

    auto compute = [&](int buf) {
        const char* base = ldsb + buf * 16384;
        f16x8 af[4], bf[4];
        #pragma unroll
        for (int mt = 0; mt < 4; ++mt) {
            const int row = wm * 64 + mt * 16 + lr;
            af[mt] = *(const f16x8*)(base + row * 64 + ((sl ^ ((row >> 1) & 3)) << 4));
        }
        #pragma unroll
        for (int nt = 0; nt < 4; ++nt) {
            const int row = wn * 64 + nt * 16 + lr;
            bf[nt] = *(const f16x8*)(base + 8192 + row * 64 + ((sl ^ ((row >> 1) & 3)) << 4));
        }
        #pragma unroll
        for (int mt = 0; mt < 4; ++mt)
            #pragma unroll
            for (int nt = 0; nt < 4; ++nt)
                acc[mt][nt] = __builtin_amdgcn_mfma_f32_16x16x32_f16(
                    af[mt], bf[nt], acc[mt][nt], 0, 0, 0);
    };

    stage(0, 0);
    stage(1, 1);

    #pragma unroll
    for (int t = 0; t < 7; ++t) {
        asm volatile("s_waitcnt vmcnt(4)" ::: "memory");   // stage(t) landed
        __builtin_amdgcn_s_barrier();
        __builtin_amdgcn_sched_barrier(0);
        if (t < 6) stage(t + 2, (t + 2) % 3);              // stays in flight
        compute(t % 3);
    }
    asm volatile("s_waitcnt vmcnt(0)" ::: "memory");
    __builtin_amdgcn_s_barrier();
    __builtin_amdgcn_sched_barrier(0);
    compute(7 % 3);

    // ---- epilogue: transpose through LDS, 16B coalesced stores ----
    __syncthreads();
    _Float16* et = (_Float16*)ldsb;           // [128][136] fp16 = 34816 B
    #pragma unroll
    for (int mt = 0; mt < 4; ++mt)
        #pragma unroll
        for (int nt = 0; nt < 4; ++nt)
            #pragma unroll
            for (int jv = 0; jv < 4; ++jv) {
                const int row = wm * 64 + mt * 16 + sl * 4 + jv;  // 0..127
                const int col = wn * 64 + nt * 16 + lr;           // 0..127
                et[row * 136 + col] = (_Float16)acc[mt][nt][jv];
            }
    __syncthreads();
    const size_t zoff = z * ND;
    #pragma unroll
    for (int qq = 0; qq < 8; ++qq) {
        const int c   = qq * 256 + tid;       // 0..2047 16B-chunk id
        const int row = c >> 4;               // 0..127
        const int cc  = (c & 15) * 8;         // f16 col 0..120
        const int orow = bm0 + row;
        if (orow < En) {
            const f16x8 v = *(const f16x8*)(et + row * 136 + cc);
            *(f16x8*)(C16 + zoff + (size_t)orow * DIM + bn0 + cc) = v;
        }
    }
}

// ---------------------------------------------------------------------------
__global__ __launch_bounds__(256)
void convert_w(const float* __restrict__ Wctr, const float* __restrict__ Wctr2,
               const float* __restrict__ Wpre, const float* __restrict__ Wsuc,
               _Float16* __restrict__ WH)
{
    const size_t i4 = (size_t)blockIdx.x * 256 + threadIdx.x;
    const size_t NT = (size_t)56 * DIM * DIM / 4;
    if (i4 >= NT) return;
    const size_t e = i4 * 4;
    const int slot = (int)(e >> 16);
    const int off  = (int)(e & 65535);
    const float* src;
    if (slot < 48) {
        const int r = slot / 12, s = slot % 12, k = s >> 1, dir = s & 1;
        src = (dir ? Wsuc : Wpre) + (((size_t)r * SHOPS + k) << 16) + off;
    } else if (slot < 52) {
        src = Wctr + ((size_t)(slot - 48) << 16) + off;
    } else {
        src = Wctr2 + ((size_t)(slot - 52) << 16) + off;
    }
    const float4 v = *(const float4*)src;
    f16x4 h;
    h[0] = (_Float16)v.x; h[1] = (_Float16)v.y;
    h[2] = (_Float16)v.z; h[3] = (_Float16)v.w;
    *(f16x4*)(WH + e) = h;
}

__global__ __launch_bounds__(256)
void init_x(const float* __restrict__ lane, _Float16* __restrict__ Xh)
{
    const size_t i4 = (size_t)blockIdx.x * 256 + threadIdx.x;
    if (i4 >= ND / 4) return;
    const float4 v = *(const float4*)(lane + i4 * 4);
    f16x4 h;
    h[0] = (_Float16)v.x; h[1] = (_Float16)v.y;
    h[2] = (_Float16)v.z; h[3] = (_Float16)v.w;
    *(f16x4*)(Xh + i4 * 4) = h;
}

template<int WRITEX>
__global__ __launch_bounds__(256)
void gn1_kernel(const _Float16* __restrict__ inh, const float* __restrict__ w,
                const float* __restrict__ b, const _Float16* __restrict__ resh,
                float* __restrict__ X, _Float16* __restrict__ Xh)
{
    const int lane = threadIdx.x & 63;
    const int wv   = threadIdx.x >> 6;
    const int row  = blockIdx.x * 4 + wv;
    if (row >= NROWS) return;
    const size_t rowoff = (size_t)row * DIM + lane * 4;

    const f16x4 hv = *(const f16x4*)(inh + rowoff);
    float4 v;
    v.x = (float)hv[0]; v.y = (float)hv[1]; v.z = (float)hv[2]; v.w = (float)hv[3];
    float s  = v.x + v.y + v.z + v.w;
    float ss = v.x * v.x + v.y * v.y + v.z * v.z + v.w * v.w;
    #pragma unroll
    for (int off = 32; off >= 1; off >>= 1) {
        s  += __shfl_xor(s, off);
        ss += __shfl_xor(ss, off);
    }
    const float m   = s * (1.0f / DIM);
    const float var = ss * (1.0f / DIM) - m * m;
    const float inv = rsqrtf(var + EPSV);

    const float4 wv4 = *(const float4*)(w + lane * 4);
    const float4 bv4 = *(const float4*)(b + lane * 4);
    const f16x4  r4  = *(const f16x4*)(resh + rowoff);
    float4 o;
    o.x = fmaxf((v.x - m) * inv * wv4.x + bv4.x + (float)r4[0], 0.f);
    o.y = fmaxf((v.y - m) * inv * wv4.y + bv4.y + (float)r4[1], 0.f);
    o.z = fmaxf((v.z - m) * inv * wv4.z + bv4.z + (float)r4[2], 0.f);
    o.w = fmaxf((v.w - m) * inv * wv4.w + bv4.w + (float)r4[3], 0.f);
    if (WRITEX)
        *(float4*)(X + rowoff) = o;
    f16x4 oh;
    oh[0] = (_Float16)o.x; oh[1] = (_Float16)o.y;
    oh[2] = (_Float16)o.z; oh[3] = (_Float16)o.w;
    *(f16x4*)(Xh + rowoff) = oh;
}

// ---------------------------------------------------------------------------
// Prep: live-row analysis + CSR inversion with per-chunk split (once/launch)
// ---------------------------------------------------------------------------
__global__ __launch_bounds__(256)
void markk(const int* __restrict__ nhp, const int* __restrict__ nhs,
           int* __restrict__ mark)
{
    const int i = blockIdx.x * 256 + threadIdx.x;
    if (i >= NROWS) return;
    const int s = blockIdx.y;
    const int k = s >> 1, dir = s & 1;
    const int* gp = (dir ? nhs : nhp) + k * NROWS;
    mark[(size_t)s * NROWS + gp[i]] = 1;
}

__global__ __launch_bounds__(256)
void mscan1(const int* __restrict__ mark, int* __restrict__ mrank,
            int* __restrict__ msum)
{
    __shared__ int wsum[4];
    const int s = blockIdx.y;
    const int tid = threadIdx.x, lane = tid & 63, wv = tid >> 6;
    const int i = blockIdx.x * 256 + tid;
    const int c = (i < NROWS) ? mark[(size_t)s * NROWS + i] : 0;
    int v = c;
    #pragma unroll
    for (int off = 1; off < 64; off <<= 1) {
        const int t = __shfl_up(v, off);
        if (lane >= off) v += t;
    }
    if (lane == 63) wsum[wv] = v;
    __syncthreads();
    int add = 0;
    for (int w = 0; w < wv; ++w) add += wsum[w];
    if (i < NROWS) mrank[(size_t)s * NROWS + i] = add + v - c;
    if (tid == 255) msum[s * 256 + blockIdx.x] = wsum[0] + wsum[1] + wsum[2] + wsum[3];
}

__global__ __launch_bounds__(256)
void mscan2(const int* __restrict__ msum, int* __restrict__ mbpre,
            int* __restrict__ Ecnt)
{
    __shared__ int wsum[4];
    const int s = blockIdx.x;
    const int tid = threadIdx.x, lane = tid & 63, wv = tid >> 6;
    const int c = (tid < NB) ? msum[s * 256 + tid] : 0;
    int v = c;
    #pragma unroll
    for (int off = 1; off < 64; off <<= 1) {
        const int t = __shfl_up(v, off);
        if (lane >= off) v += t;
    }
    if (lane == 63) wsum[wv] = v;
    __syncthreads();
    int add = 0;
    for (int w = 0; w < wv; ++w) add += wsum[w];
    if (tid < NB) mbpre[s * 256 + tid] = add + v - c;
    if (tid == 0) Ecnt[s] = wsum[0] + wsum[1] + wsum[2] + wsum[3];
}

__global__ __launch_bounds__(256)
void mscan3(const int* __restrict__ mark, int* __restrict__ mrank,
            const int* __restrict__ mbpre, int* __restrict__ live)
{
    const int i = blockIdx.x * 256 + threadIdx.x;
    if (i >= NROWS) return;
    const int s = blockIdx.y;
    const size_t o = (size_t)s * NROWS + i;
    const int rk = mrank[o] + mbpre[s * 256 + blockIdx.x];
    mrank[o] = rk;
    if (mark[o]) live[(size_t)s * NROWS + rk] = i;
}

// counts: all 12 segs; countsA: segs 0..5 only (chunk-A split)
__global__ __launch_bounds__(256)
void count_kernel(const int* __restrict__ pidx, const int* __restrict__ sidx,
                  int* __restrict__ counts, int* __restrict__ countsA)
{
    const int i = blockIdx.x * 256 + threadIdx.x;
    if (i >= NROWS) return;
    const int s = blockIdx.y;
    const int k = s >> 1, dir = s & 1;
    const int* scp = (dir ? pidx : sidx) + k * NROWS;
    const int dst = scp[i];
    atomicAdd(&counts[dst], 1);
    if (s < 6) atomicAdd(&countsA[dst], 1);
}

__global__ __launch_bounds__(256)
void scan1_kernel(const int* __restrict__ counts, int* __restrict__ offs,
                  int* __restrict__ bsum)
{
    __shared__ int wsum[4];
    const int tid = threadIdx.x, lane = tid & 63, wv = tid >> 6;
    const int i = blockIdx.x * 256 + tid;
    const int c = (i < NROWS) ? counts[i] : 0;
    int v = c;
    #pragma unroll
    for (int off = 1; off < 64; off <<= 1) {
        const int t = __shfl_up(v, off);
        if (lane >= off) v += t;
    }
    if (lane == 63) wsum[wv] = v;
    __syncthreads();
    int add = 0;
    for (int w = 0; w < wv; ++w) add += wsum[w];
    if (i < NROWS) offs[i] = add + v - c;
    if (tid == 255) bsum[blockIdx.x] = wsum[0] + wsum[1] + wsum[2] + wsum[3];
}

__global__ __launch_bounds__(256)
void scan2_kernel(const int* __restrict__ bsum, int* __restrict__ bpre)
{
    __shared__ int wsum[4];
    const int tid = threadIdx.x, lane = tid & 63, wv = tid >> 6;
    const int c = (tid < NB) ? bsum[tid] : 0;
    int v = c;
    #pragma unroll
    for (int off = 1; off < 64; off <<= 1) {
        const int t = __shfl_up(v, off);
        if (lane >= off) v += t;
    }
    if (lane == 63) wsum[wv] = v;
    __syncthreads();
    int add = 0;
    for (int w = 0; w < wv; ++w) add += wsum[w];
    if (tid < NB) bpre[tid] = add + v - c;
}

// finalize offsets; mid[r] = offs[r] + countsA[r]; init both cursors
__global__ __launch_bounds__(256)
void scan3_kernel(int* __restrict__ offs, const int* __restrict__ bpre,
                  const int* __restrict__ countsA,
                  int* __restrict__ cursorA, int* __restrict__ cursorB,
                  int* __restrict__ mid)
{
    const int i = blockIdx.x * 256 + threadIdx.x;
    if (i < NROWS) {
        const int v = offs[i] + bpre[blockIdx.x];
        offs[i] = v;
        cursorA[i] = v;
        const int m = v + countsA[i];
        mid[i] = m;
        cursorB[i] = m;
    }
    if (i == 0) offs[NROWS] = 12 * NROWS;
}

// entries: (seg << 16) | rank, chunk-A entries before mid, chunk-B after
__global__ __launch_bounds__(256)
void fill_kernel(const int* __restrict__ pidx, const int* __restrict__ sidx,
                 const int* __restrict__ nhp, const int* __restrict__ nhs,
                 const int* __restrict__ mrank,
                 int* __restrict__ cursorA, int* __restrict__ cursorB,
                 int* __restrict__ entries)
{
    const int i = blockIdx.x * 256 + threadIdx.x;
    if (i >= NROWS) return;
    const int s = blockIdx.y;
    const int k = s >> 1, dir = s & 1;
    const int* scp = (dir ? pidx : sidx) + k * NROWS;
    const int* gp  = (dir ? nhs  : nhp)  + k * NROWS;
    const int dst = scp[i];
    const int pos = (s < 6) ? atomicAdd(&cursorA[dst], 1)
                            : atomicAdd(&cursorB[dst], 1);
    entries[pos] = (s << 16) | mrank[(size_t)s * NROWS + gp[i]];
}

// ---------------------------------------------------------------------------
// combine: half=0 -> entries [offs, mid); half=1 -> [mid, offs+1); -1 -> all.
// ---------------------------------------------------------------------------
template<int FIRST, int LAST>
__global__ __launch_bounds__(256)
void combine_f16(const _Float16* __restrict__ YC, _Float16* __restrict__ TEMP16,
                 const _Float16* __restrict__ YB,
                 const int* __restrict__ offsets, const int* __restrict__ mid,
                 const int* __restrict__ entries,
                 int c0, int nch, int half,
                 const float* __restrict__ gw, const float* __restrict__ gb,
                 _Float16* __restrict__ Hh)
{
    const int lane = threadIdx.x & 63;
    const int wv   = threadIdx.x >> 6;
    const int r    = blockIdx.x * 4 + wv;
    if (r >= NROWS) return;
    const size_t rowoff = (size_t)r * DIM + lane * 4;

    const f16x4 iv = FIRST ? *(const f16x4*)(YC + rowoff)
                           : *(const f16x4*)(TEMP16 + rowoff);
    float4 acc;
    acc.x = (float)iv[0]; acc.y = (float)iv[1];
    acc.z = (float)iv[2]; acc.w = (float)iv[3];

    int e0, e1;
    if (half == 0)      { e0 = offsets[r]; e1 = mid[r]; }
    else if (half == 1) { e0 = mid[r];     e1 = offsets[r + 1]; }
    else                { e0 = offsets[r]; e1 = offsets[r + 1]; }

    for (int e = e0; e < e1; ++e) {
        const int ent = entries[e];
        const int s = ent >> 16;
        if ((unsigned)(s - c0) < (unsigned)nch) {
            const f16x4 yv = *(const f16x4*)(YB + (size_t)(s - c0) * ND
                                             + (size_t)(ent & 0xFFFF) * DIM + lane * 4);
            acc.x += (float)yv[0]; acc.y += (float)yv[1];
            acc.z += (float)yv[2]; acc.w += (float)yv[3];
        }
    }

    if (LAST) {
        float s  = acc.x + acc.y + acc.z + acc.w;
        float ss = acc.x * acc.x + acc.y * acc.y + acc.z * acc.z + acc.w * acc.w;
        #pragma unroll
        for (int off = 32; off >= 1; off >>= 1) {
            s  += __shfl_xor(s, off);
            ss += __shfl_xor(ss, off);
        }
        const float m   = s * (1.0f / DIM);
        const float var = ss * (1.0f / DIM) - m * m;
        const float inv = rsqrtf(var + EPSV);
        const float4 wv4 = *(const float4*)(gw + lane * 4);
        const float4 bv4 = *(const float4*)(gb + lane * 4);
        f16x4 o;
        o[0] = (_Float16)fmaxf((acc.x - m) * inv * wv4.x + bv4.x, 0.f);
        o[1] = (_Float16)fmaxf((acc.y - m) * inv * wv4.y + bv4.y, 0.f);
        o[2] = (_Float16)fmaxf((acc.z - m) * inv * wv4.z + bv4.z, 0.f);
        o[3] = (_Float16)fmaxf((acc.w - m) * inv * wv4.w + bv4.w, 0.f);
        *(f16x4*)(Hh + rowoff) = o;
    } else {
        f16x4 o;
        o[0] = (_Float16)acc.x; o[1] = (_Float16)acc.y;
        o[2] = (_Float16)acc.z; o[3] = (_Float16)acc.w;
        *(f16x4*)(TEMP16 + rowoff) = o;
    }
}

// ---------------------------------------------------------------------------
extern "C" void kernel_launch(void* const* d_in, const int* in_sizes, int n_in,
                              void* d_out, int out_size, void* d_ws, size_t ws_size,
                              hipStream_t stream)
{
    const float* lane   = (const float*)d_in[0];
    const float* W_ctr  = (const float*)d_in[1];
    const float* norm_w = (const float*)d_in[2];
    const float* norm_b = (const float*)d_in[3];
    const float* W_ctr2 = (const float*)d_in[4];
    const float* c2w    = (const float*)d_in[5];
    const float* c2b    = (const float*)d_in[6];
    const float* W_pre  = (const float*)d_in[7];
    const float* W_suc  = (const float*)d_in[8];
    const int*   pidx   = (const int*)d_in[9];
    const int*   sidx   = (const int*)d_in[10];
    const int*   nhp    = (const int*)d_in[11];
    const int*   nhs    = (const int*)d_in[12];

    float* X = (float*)d_out;

    // ---- workspace layout (YC must immediately precede YBUF) ----
    char* p = (char*)d_ws;
    int* counts  = (int*)p; p += (size_t)NROWS * 4;
    int* countsA = (int*)p; p += (size_t)NROWS * 4;
    int* offsets = (int*)p; p += (size_t)(NROWS + 4) * 4;
    int* mid     = (int*)p; p += (size_t)NROWS * 4;
    int* cursorA = (int*)p; p += (size_t)NROWS * 4;
    int* cursorB = (int*)p; p += (size_t)NROWS * 4;
    int* bsum    = (int*)p; p += 256 * 4;
    int* bpre    = (int*)p; p += 256 * 4;
    int* msum    = (int*)p; p += 12 * 256 * 4;
    int* mbpre   = (int*)p; p += 12 * 256 * 4;
    int* Ecnt    = (int*)p; p += 16 * 4;
    int* entries = (int*)p; p += (size_t)12 * NROWS * 4;
    int* LIVE    = (int*)p; p += (size_t)12 * NROWS * 4;
    p = (char*)(((uintptr_t)p + 15) & ~(uintptr_t)15);
    _Float16* Xh   = (_Float16*)p; p += ND * 2;
    _Float16* Hh   = (_Float16*)p; p += ND * 2;
    _Float16* T16  = (_Float16*)p; p += ND * 2;
    _Float16* WH   = (_Float16*)p; p += (size_t)56 * DIM * DIM * 2;
    p = (char*)(((uintptr_t)p + 15) & ~(uintptr_t)15);
    _Float16* YC   = (_Float16*)p; p += ND * 2;
    _Float16* YBUF = (_Float16*)p;            // contiguous after YC

    // prep-only arrays aliased into YBUF (used strictly before first GEMM)
    int* mark  = (int*)YBUF;
    int* mrank = mark + (size_t)12 * NROWS;

    const size_t used = (size_t)(p - (char*)d_ws);
    int nslot = (int)((ws_size - used) / (ND * 2));
    if (nslot < 1) nslot = 1;
    int CH = nslot > 12 ? 12 : nslot;
    const int nchunks = (12 + CH - 1) / CH;
    CH = (12 + nchunks - 1) / nchunks;
    _Float16* Y2 = YBUF;                      // ctr2 output reuses slot 0

    const dim3 blk(256);
    const int  gnBlocks = (NROWS + 3) / 4;
    const int  cwBlocks = (int)(((size_t)56 * DIM * DIM / 4 + 255) / 256);
    const int  ixBlocks = (int)((ND / 4 + 255) / 256);

    // one-time prep
    convert_w<<<cwBlocks, blk, 0, stream>>>(W_ctr, W_ctr2, W_pre, W_suc, WH);
    init_x<<<ixBlocks, blk, 0, stream>>>(lane, Xh);
    hipMemsetAsync(counts, 0, NROWS * sizeof(int), stream);
    hipMemsetAsync(countsA, 0, NROWS * sizeof(int), stream);
    hipMemsetAsync(mark, 0, (size_t)12 * NROWS * sizeof(int), stream);
    markk<<<dim3(NB, 12), blk, 0, stream>>>(nhp, nhs, mark);
    mscan1<<<dim3(NB, 12), blk, 0, stream>>>(mark, mrank, msum);
    mscan2<<<12, blk, 0, stream>>>(msum, mbpre, Ecnt);
    mscan3<<<dim3(NB, 12), blk, 0, stream>>>(mark, mrank, mbpre, LIVE);
    count_kernel<<<dim3(NB, 12), blk, 0, stream>>>(pidx, sidx, counts, countsA);
    scan1_kernel<<<NB, blk, 0, stream>>>(counts, offsets, bsum);
    scan2_kernel<<<1, blk, 0, stream>>>(bsum, bpre);
    scan3_kernel<<<NB, blk, 0, stream>>>(offsets, bpre, countsA,
                                         cursorA, cursorB, mid);
    fill_kernel<<<dim3(NB, 12), blk, 0, stream>>>(pidx, sidx, nhp, nhs, mrank,
                                                  cursorA, cursorB, entries);

    for (int i = 0; i < ROUNDS; ++i) {
        for (int c0 = 0; c0 < 12; c0 += CH) {
            const int nz  = (12 - c0 < CH) ? (12 - c0) : CH;
            const bool first = (c0 == 0);
            const bool last  = (c0 + nz >= 12);
            if (first) {
                const int nwg = 391 * 2 * (nz + 1);
                gemm_p<<<dim3(nwg), blk, 0, stream>>>(Xh, WH, 48 + i,
                    i * 12 + c0 - 1, nz + 1, YC, nwg, LIVE, Ecnt, c0 - 1);
            } else {
                const int nwg = 391 * 2 * nz;
                gemm_p<<<dim3(nwg), blk, 0, stream>>>(Xh, WH, i * 12 + c0,
                    i * 12 + c0, nz, YBUF, nwg, LIVE, Ecnt, c0);
            }
            // half split valid only for the canonical CH=6 two-chunk case
            const int half = (CH == 6) ? (first ? 0 : 1) : -1;
            if (first && last)
                combine_f16<1, 1><<<gnBlocks, blk, 0, stream>>>(YC, T16, YBUF,
                    offsets, mid, entries, c0, nz, half,
                    norm_w + i * DIM, norm_b + i * DIM, Hh);
            else if (first)
                combine_f16<1, 0><<<gnBlocks, blk, 0, stream>>>(YC, T16, YBUF,
                    offsets, mid, entries, c0, nz, half,
                    norm_w + i * DIM, norm_b + i * DIM, Hh);
            else if (last)
                combine_f16<0, 1><<<gnBlocks, blk, 0, stream>>>(YC, T16, YBUF,
                    offsets, mid, entries, c0, nz, half,
                    norm_w + i * DIM, norm_b + i * DIM, Hh);
            else
                combine_f16<0, 0><<<gnBlocks, blk, 0, stream>>>(YC, T16, YBUF,
                    offsets, mid, entries, c0, nz, half,
                    norm_w + i * DIM, norm_b + i * DIM, Hh);
        }
        // y = h @ W_ctr2[i].T (identity rows)
        {
            const int nwg = 391 * 2;
            gemm_p<<<dim3(nwg), blk, 0, stream>>>(Hh, WH, 52 + i, 52 + i, 1,
                                                  Y2, nwg, LIVE, Ecnt, -1000);
        }
        // x = relu(gn(y) + x); fp32 X written only in the final round
        if (i == ROUNDS - 1)
            gn1_kernel<1><<<gnBlocks, blk, 0, stream>>>(Y2, c2w + i * DIM,
                                                        c2b + i * DIM, Xh, X, Xh);
        else
            gn1_kernel<0><<<gnBlocks, blk, 0, stream>>>(Y2, c2w + i * DIM,
                                                        c2b + i * DIM, Xh, X, Xh);
    }
}

// Round 12
// 1076.549 us; speedup vs baseline: 1.3774x; 1.2154x over previous
//
#include <hip/hip_runtime.h>

#define NROWS 50000
#define DIM   256
#define SHOPS 6
#define ROUNDS 4
#define EPSV  1e-5f
#define ND ((size_t)NROWS * DIM)
#define NB  196                              // ceil(NROWS/256)
#define EMAXR 36864                          // compacted-slot row bound (live rows ~31.6K +- ~100)
#define EMAXND ((size_t)EMAXR * DIM)

typedef _Float16 f16x8 __attribute__((ext_vector_type(8)));
typedef _Float16 f16x4 __attribute__((ext_vector_type(4)));
typedef float    f32x4 __attribute__((ext_vector_type(4)));

#define GLDS16(GP, LP) \
    __builtin_amdgcn_global_load_lds((const __attribute__((address_space(1))) unsigned*)(GP), \
                                     (__attribute__((address_space(3))) unsigned*)(LP), 16, 0, 0)

__device__ __forceinline__ int imin(int a, int b) { return a < b ? a : b; }

// ---------------------------------------------------------------------------
// Pipelined fp16 MFMA GEMM, A-side gather + compacted output (r11 structure:
// panel-spread XCD swizzle, 3-buf counted-vmcnt, 64B-row XOR swizzle,
// LDS-transposed epilogue). Slot z: weight wslot(z)= z==0 ? s0 : s1+z;
// segment seg = sbase+z (seg<0 -> identity rows, full NROWS, dest C0);
// compacted slots write CZ + (z-ctr0)*EMAXND.
// ---------------------------------------------------------------------------
__global__ __launch_bounds__(256)
void gemm_p(const _Float16* __restrict__ A, const _Float16* __restrict__ WH,
            int s0, int s1, int nz, _Float16* __restrict__ C0,
            _Float16* __restrict__ CZ, int ctr0, int nwg,
            const int* __restrict__ LIVE, const int* __restrict__ Ecnt,
            int sbase)
{
    __shared__ _Float16 lds[3][8192];        // 3 x (A 8KB + W 8KB) = 48KB
    char* ldsb = (char*)lds;

    // bijective XCD chunking; then panel-spread unchunk (mod-8 panels per XCD)
    const int bid = blockIdx.x;
    const int q   = nwg >> 3, r = nwg & 7;
    const int xcd = bid & 7,  ii = bid >> 3;
    const int g   = (xcd < r) ? xcd * (q + 1) + ii
                              : r * (q + 1) + (xcd - r) * q + ii;
    const int j   = g / (2 * nz);
    const int sub = g - j * 2 * nz;
    const int by  = sub & 1;
    const size_t z = sub >> 1;
    int xp, jj;
    if (j < 7 * 49) { xp = j / 49; jj = j % 49; }
    else            { xp = 7; jj = j - 7 * 49; }
    const int bx = jj * 8 + xp;

    const int seg = sbase + (int)z;
    const int En  = (seg >= 0) ? Ecnt[seg] : NROWS;
    const int bm0 = bx * 128;
    if (bm0 >= En) return;
    const int* lvp = (seg >= 0) ? LIVE + (size_t)seg * NROWS : nullptr;

    const int tid = threadIdx.x;
    const int l   = tid & 63;
    const int w   = tid >> 6;
    const int wm  = w & 1;
    const int wn  = w >> 1;
    const int bn0 = by * 128;
    const int lr  = l & 15;
    const int sl  = l >> 4;

    const int wslot = (z == 0) ? s0 : s1 + (int)z;
    const char* Ab = (const char*)A;
    const char* Wb = (const char*)(WH + (size_t)wslot * (DIM * DIM));

    int arow[2], slog[2], wrow[2];
    #pragma unroll
    for (int qq = 0; qq < 2; ++qq) {
        const int c   = (w * 2 + qq) * 64 + l;
        const int row = c >> 2;
        slog[qq] = (c & 3) ^ ((row >> 1) & 3);
        const int cl = imin(bm0 + row, En - 1);
        arow[qq] = lvp ? lvp[cl] : cl;
        wrow[qq] = bn0 + row;
    }

    f32x4 acc[4][4];
    #pragma unroll
    for (int mt = 0; mt < 4; ++mt)
        #pragma unroll
        for (int nt = 0; nt < 4; ++nt)
            acc[mt][nt] = (f32x4){0.f, 0.f, 0.f, 0.f};

    auto stage = [&](int step, int buf) {
        const int kt64 = step * 64;
        char* base = ldsb + buf * 16384;
        #pragma unroll
        for (int qq = 0; qq < 2; ++qq) {
            GLDS16(Ab + (size_t)arow[qq] * 512 + kt64 + slog[qq] * 16,
                   base + (w * 2 + qq) * 1024);
            GLDS16(Wb + (size_t)wrow[qq] * 512 + kt64 + slog[qq] * 16,
                   base + 8192 + (w * 2 + qq) * 1024);
        }
    };

    auto compute = [&](int buf) {
        const char* base = ldsb + buf * 16384;
        f16x8 af[4], bf[4];
        #pragma unroll
        for (int mt = 0; mt < 4; ++mt) {
            const int row = wm * 64 + mt * 16 + lr;
            af[mt] = *(const f16x8*)(base + row * 64 + ((sl ^ ((row >> 1) & 3)) << 4));
        }
        #pragma unroll
        for (int nt = 0; nt < 4; ++nt) {
            const int row = wn * 64 + nt * 16 + lr;
            bf[nt] = *(const f16x8*)(base + 8192 + row * 64 + ((sl ^ ((row >> 1) & 3)) << 4));
        }
        #pragma unroll
        for (int mt = 0; mt < 4; ++mt)
            #pragma unroll
            for (int nt = 0; nt < 4; ++nt)
                acc[mt][nt] = __builtin_amdgcn_mfma_f32_16x16x32_f16(
                    af[mt], bf[nt], acc[mt][nt], 0, 0, 0);
    };

    stage(0, 0);
    stage(1, 1);
    #pragma unroll
    for (int t = 0; t < 7; ++t) {
        asm volatile("s_waitcnt vmcnt(4)" ::: "memory");
        __builtin_amdgcn_s_barrier();
        __builtin_amdgcn_sched_barrier(0);
        if (t < 6) stage(t + 2, (t + 2) % 3);
        compute(t % 3);
    }
    asm volatile("s_waitcnt vmcnt(0)" ::: "memory");
    __builtin_amdgcn_s_barrier();
    __builtin_amdgcn_sched_barrier(0);
    compute(7 % 3);

    __syncthreads();
    _Float16* et = (_Float16*)ldsb;           // [128][136]
    #pragma unroll
    for (int mt = 0; mt < 4; ++mt)
        #pragma unroll
        for (int nt = 0; nt < 4; ++nt)
            #pragma unroll
            for (int jv = 0; jv < 4; ++jv) {
                const int row = wm * 64 + mt * 16 + sl * 4 + jv;
                const int col = wn * 64 + nt * 16 + lr;
                et[row * 136 + col] = (_Float16)acc[mt][nt][jv];
            }
    __syncthreads();
    _Float16* Cb = (ctr0 && z == 0) ? C0 : CZ + (size_t)((int)z - ctr0) * EMAXND;
    #pragma unroll
    for (int qq = 0; qq < 8; ++qq) {
        const int c   = qq * 256 + tid;
        const int row = c >> 4;
        const int cc  = (c & 15) * 8;
        const int orow = bm0 + row;
        if (orow < En) {
            const f16x8 v = *(const f16x8*)(et + row * 136 + cc);
            *(f16x8*)(Cb + (size_t)orow * DIM + bn0 + cc) = v;
        }
    }
}

// ---------------------------------------------------------------------------
// Fused ctr2 GEMM + GroupNorm + residual + ReLU.
// 512 thr (8 waves: wm=w&1 row-half, wn=w>>1 col-quarter), tile 128x256,
// 2-buf pipeline (A 8KB + W 16KB per buf), stats LDS at 48KB (+4KB).
// out: Xh = relu(gn(Hh @ W^T)*gw+gb + Xh); X fp32 too iff writex.
// ---------------------------------------------------------------------------
__global__ __launch_bounds__(512)
void gemm_gn(const _Float16* __restrict__ A, const _Float16* __restrict__ WH,
             int wslot, const float* __restrict__ gw, const float* __restrict__ gb,
             float* __restrict__ X, _Float16* __restrict__ Xh, int writex)
{
    __shared__ char ldsb[49152 + 4096];
    float* sArr  = (float*)(ldsb + 49152);    // [4][128]
    float* ssArr = sArr + 512;                // [4][128]

    const int tid = threadIdx.x;
    const int l   = tid & 63;
    const int w   = tid >> 6;                 // 0..7
    const int wm  = w & 1;
    const int wn  = w >> 1;                   // 0..3
    const int bm0 = blockIdx.x * 128;
    const int lr  = l & 15;
    const int sl  = l >> 4;

    const char* Ab = (const char*)A;
    const char* Wb = (const char*)(WH + (size_t)wslot * (DIM * DIM));

    // staging geometry: A chunk=tid (512 chunks); W chunks tid, tid+512
    int arow, aslog, wr0, ws0, wr1, ws1;
    {
        int c = tid, row = c >> 2;
        aslog = (c & 3) ^ ((row >> 1) & 3);
        arow  = imin(bm0 + row, NROWS - 1);
        ws0 = aslog; wr0 = row;                       // W rows 0..127 share c
        c = tid + 512; row = c >> 2;                  // 128..255
        ws1 = (c & 3) ^ ((row >> 1) & 3); wr1 = row;
    }

    f32x4 acc[4][4];
    #pragma unroll
    for (int mt = 0; mt < 4; ++mt)
        #pragma unroll
        for (int nt = 0; nt < 4; ++nt)
            acc[mt][nt] = (f32x4){0.f, 0.f, 0.f, 0.f};

    auto stage = [&](int step, int buf) {
        const int kt64 = step * 64;
        char* base = ldsb + buf * 24576;
        GLDS16(Ab + (size_t)arow * 512 + kt64 + aslog * 16, base + w * 1024);
        GLDS16(Wb + (size_t)wr0 * 512 + kt64 + ws0 * 16, base + 8192 + w * 1024);
        GLDS16(Wb + (size_t)wr1 * 512 + kt64 + ws1 * 16, base + 16384 + w * 1024);
    };

    auto compute = [&](int buf) {
        const char* base = ldsb + buf * 24576;
        f16x8 af[4], bf[4];
        #pragma unroll
        for (int mt = 0; mt < 4; ++mt) {
            const int row = wm * 64 + mt * 16 + lr;
            af[mt] = *(const f16x8*)(base + row * 64 + ((sl ^ ((row >> 1) & 3)) << 4));
        }
        #pragma unroll
        for (int nt = 0; nt < 4; ++nt) {
            const int row = wn * 64 + nt * 16 + lr;   // 0..255
            bf[nt] = *(const f16x8*)(base + 8192 + row * 64 + ((sl ^ ((row >> 1) & 3)) << 4));
        }
        #pragma unroll
        for (int mt = 0; mt < 4; ++mt)
            #pragma unroll
            for (int nt = 0; nt < 4; ++nt)
                acc[mt][nt] = __builtin_amdgcn_mfma_f32_16x16x32_f16(
                    af[mt], bf[nt], acc[mt][nt], 0, 0, 0);
    };

    stage(0, 0);
    #pragma unroll
    for (int t = 0; t < 8; ++t) {
        asm volatile("s_waitcnt vmcnt(0)" ::: "memory");
        __builtin_amdgcn_s_barrier();
        __builtin_amdgcn_sched_barrier(0);
        if (t < 7) stage(t + 1, (t + 1) & 1);
        compute(t & 1);
    }

    // ---- GN stats: per-lane partials over this wave's 64 cols ----
    float sp[4][4], ssp[4][4];
    #pragma unroll
    for (int mt = 0; mt < 4; ++mt)
        #pragma unroll
        for (int jv = 0; jv < 4; ++jv) {
            float s = 0.f, ss = 0.f;
            #pragma unroll
            for (int nt = 0; nt < 4; ++nt) {
                const float v = acc[mt][nt][jv];
                s += v; ss += v * v;
            }
            sp[mt][jv] = s; ssp[mt][jv] = ss;
        }
    #pragma unroll
    for (int off = 1; off < 16; off <<= 1)
        #pragma unroll
        for (int mt = 0; mt < 4; ++mt)
            #pragma unroll
            for (int jv = 0; jv < 4; ++jv) {
                sp[mt][jv]  += __shfl_xor(sp[mt][jv], off);
                ssp[mt][jv] += __shfl_xor(ssp[mt][jv], off);
            }
    __syncthreads();                          // pipeline area free; stats area fresh
    if (lr == 0) {
        #pragma unroll
        for (int mt = 0; mt < 4; ++mt)
            #pragma unroll
            for (int jv = 0; jv < 4; ++jv) {
                const int row = wm * 64 + mt * 16 + sl * 4 + jv;
                sArr[wn * 128 + row]  = sp[mt][jv];
                ssArr[wn * 128 + row] = ssp[mt][jv];
            }
    }
    __syncthreads();
    float mv[4][4], iv[4][4];
    #pragma unroll
    for (int mt = 0; mt < 4; ++mt)
        #pragma unroll
        for (int jv = 0; jv < 4; ++jv) {
            const int row = wm * 64 + mt * 16 + sl * 4 + jv;
            const float S  = sArr[row] + sArr[128 + row] + sArr[256 + row] + sArr[384 + row];
            const float SS = ssArr[row] + ssArr[128 + row] + ssArr[256 + row] + ssArr[384 + row];
            const float m  = S * (1.0f / DIM);
            mv[mt][jv] = m;
            iv[mt][jv] = rsqrtf(SS * (1.0f / DIM) - m * m + EPSV);
        }
    float gwv[4], gbv[4];
    #pragma unroll
    for (int nt = 0; nt < 4; ++nt) {
        const int col = wn * 64 + nt * 16 + lr;
        gwv[nt] = gw[col]; gbv[nt] = gb[col];
    }

    // ---- two half-tiles: scale -> transpose -> +res, relu, store ----
    _Float16* et = (_Float16*)ldsb;           // [64][264]
    #pragma unroll
    for (int half = 0; half < 2; ++half) {
        __syncthreads();
        if (wm == half) {
            #pragma unroll
            for (int mt = 0; mt < 4; ++mt)
                #pragma unroll
                for (int nt = 0; nt < 4; ++nt)
                    #pragma unroll
                    for (int jv = 0; jv < 4; ++jv) {
                        const int rl  = mt * 16 + sl * 4 + jv;
                        const int col = wn * 64 + nt * 16 + lr;
                        et[rl * 264 + col] = (_Float16)((acc[mt][nt][jv] - mv[mt][jv])
                                                        * iv[mt][jv] * gwv[nt] + gbv[nt]);
                    }
        }
        __syncthreads();
        #pragma unroll
        for (int qq = 0; qq < 4; ++qq) {
            const int c   = qq * 512 + tid;   // 0..2047
            const int row = c >> 5;           // 0..63
            const int cc  = (c & 31) * 8;     // 0..248
            const int orow = bm0 + half * 64 + row;
            if (orow < NROWS) {
                const f16x8 y = *(const f16x8*)(et + row * 264 + cc);
                const f16x8 rr = *(const f16x8*)(Xh + (size_t)orow * DIM + cc);
                float o[8];
                #pragma unroll
                for (int e = 0; e < 8; ++e)
                    o[e] = fmaxf((float)y[e] + (float)rr[e], 0.f);
                f16x8 oh;
                #pragma unroll
                for (int e = 0; e < 8; ++e) oh[e] = (_Float16)o[e];
                *(f16x8*)(Xh + (size_t)orow * DIM + cc) = oh;
                if (writex) {
                    float* xp = X + (size_t)orow * DIM + cc;
                    *(float4*)xp       = make_float4(o[0], o[1], o[2], o[3]);
                    *(float4*)(xp + 4) = make_float4(o[4], o[5], o[6], o[7]);
                }
            }
        }
    }
}

// ---------------------------------------------------------------------------
__global__ __launch_bounds__(256)
void convert_w(const float* __restrict__ Wctr, const float* __restrict__ Wctr2,
               const float* __restrict__ Wpre, const float* __restrict__ Wsuc,
               _Float16* __restrict__ WH)
{
    const size_t i4 = (size_t)blockIdx.x * 256 + threadIdx.x;
    const size_t NT = (size_t)56 * DIM * DIM / 4;
    if (i4 >= NT) return;
    const size_t e = i4 * 4;
    const int slot = (int)(e >> 16);
    const int off  = (int)(e & 65535);
    const float* src;
    if (slot < 48) {
        const int r = slot / 12, s = slot % 12, k = s >> 1, dir = s & 1;
        src = (dir ? Wsuc : Wpre) + (((size_t)r * SHOPS + k) << 16) + off;
    } else if (slot < 52) {
        src = Wctr + ((size_t)(slot - 48) << 16) + off;
    } else {
        src = Wctr2 + ((size_t)(slot - 52) << 16) + off;
    }
    const float4 v = *(const float4*)src;
    f16x4 h;
    h[0] = (_Float16)v.x; h[1] = (_Float16)v.y;
    h[2] = (_Float16)v.z; h[3] = (_Float16)v.w;
    *(f16x4*)(WH + e) = h;
}

__global__ __launch_bounds__(256)
void init_x(const float* __restrict__ lane, _Float16* __restrict__ Xh)
{
    const size_t i4 = (size_t)blockIdx.x * 256 + threadIdx.x;
    if (i4 >= ND / 4) return;
    const float4 v = *(const float4*)(lane + i4 * 4);
    f16x4 h;
    h[0] = (_Float16)v.x; h[1] = (_Float16)v.y;
    h[2] = (_Float16)v.z; h[3] = (_Float16)v.w;
    *(f16x4*)(Xh + i4 * 4) = h;
}

// ---------------------------------------------------------------------------
// Prep: live-row analysis + CSR inversion with per-chunk split (once/launch)
// ---------------------------------------------------------------------------
__global__ __launch_bounds__(256)
void markk(const int* __restrict__ nhp, const int* __restrict__ nhs,
           int* __restrict__ mark)
{
    const int i = blockIdx.x * 256 + threadIdx.x;
    if (i >= NROWS) return;
    const int s = blockIdx.y;
    const int k = s >> 1, dir = s & 1;
    const int* gp = (dir ? nhs : nhp) + k * NROWS;
    mark[(size_t)s * NROWS + gp[i]] = 1;
}

__global__ __launch_bounds__(256)
void mscan1(const int* __restrict__ mark, int* __restrict__ mrank,
            int* __restrict__ msum)
{
    __shared__ int wsum[4];
    const int s = blockIdx.y;
    const int tid = threadIdx.x, lane = tid & 63, wv = tid >> 6;
    const int i = blockIdx.x * 256 + tid;
    const int c = (i < NROWS) ? mark[(size_t)s * NROWS + i] : 0;
    int v = c;
    #pragma unroll
    for (int off = 1; off < 64; off <<= 1) {
        const int t = __shfl_up(v, off);
        if (lane >= off) v += t;
    }
    if (lane == 63) wsum[wv] = v;
    __syncthreads();
    int add = 0;
    for (int w = 0; w < wv; ++w) add += wsum[w];
    if (i < NROWS) mrank[(size_t)s * NROWS + i] = add + v - c;
    if (tid == 255) msum[s * 256 + blockIdx.x] = wsum[0] + wsum[1] + wsum[2] + wsum[3];
}

__global__ __launch_bounds__(256)
void mscan2(const int* __restrict__ msum, int* __restrict__ mbpre,
            int* __restrict__ Ecnt)
{
    __shared__ int wsum[4];
    const int s = blockIdx.x;
    const int tid = threadIdx.x, lane = tid & 63, wv = tid >> 6;
    const int c = (tid < NB) ? msum[s * 256 + tid] : 0;
    int v = c;
    #pragma unroll
    for (int off = 1; off < 64; off <<= 1) {
        const int t = __shfl_up(v, off);
        if (lane >= off) v += t;
    }
    if (lane == 63) wsum[wv] = v;
    __syncthreads();
    int add = 0;
    for (int w = 0; w < wv; ++w) add += wsum[w];
    if (tid < NB) mbpre[s * 256 + tid] = add + v - c;
    if (tid == 0) Ecnt[s] = wsum[0] + wsum[1] + wsum[2] + wsum[3];
}

__global__ __launch_bounds__(256)
void mscan3(const int* __restrict__ mark, int* __restrict__ mrank,
            const int* __restrict__ mbpre, int* __restrict__ live)
{
    const int i = blockIdx.x * 256 + threadIdx.x;
    if (i >= NROWS) return;
    const int s = blockIdx.y;
    const size_t o = (size_t)s * NROWS + i;
    const int rk = mrank[o] + mbpre[s * 256 + blockIdx.x];
    mrank[o] = rk;
    if (mark[o]) live[(size_t)s * NROWS + rk] = i;
}

__global__ __launch_bounds__(256)
void count_kernel(const int* __restrict__ pidx, const int* __restrict__ sidx,
                  int* __restrict__ counts, int* __restrict__ countsA)
{
    const int i = blockIdx.x * 256 + threadIdx.x;
    if (i >= NROWS) return;
    const int s = blockIdx.y;
    const int k = s >> 1, dir = s & 1;
    const int* scp = (dir ? pidx : sidx) + k * NROWS;
    const int dst = scp[i];
    atomicAdd(&counts[dst], 1);
    if (s < 6) atomicAdd(&countsA[dst], 1);
}

__global__ __launch_bounds__(256)
void scan1_kernel(const int* __restrict__ counts, int* __restrict__ offs,
                  int* __restrict__ bsum)
{
    __shared__ int wsum[4];
    const int tid = threadIdx.x, lane = tid & 63, wv = tid >> 6;
    const int i = blockIdx.x * 256 + tid;
    const int c = (i < NROWS) ? counts[i] : 0;
    int v = c;
    #pragma unroll
    for (int off = 1; off < 64; off <<= 1) {
        const int t = __shfl_up(v, off);
        if (lane >= off) v += t;
    }
    if (lane == 63) wsum[wv] = v;
    __syncthreads();
    int add = 0;
    for (int w = 0; w < wv; ++w) add += wsum[w];
    if (i < NROWS) offs[i] = add + v - c;
    if (tid == 255) bsum[blockIdx.x] = wsum[0] + wsum[1] + wsum[2] + wsum[3];
}

__global__ __launch_bounds__(256)
void scan2_kernel(const int* __restrict__ bsum, int* __restrict__ bpre)
{
    __shared__ int wsum[4];
    const int tid = threadIdx.x, lane = tid & 63, wv = tid >> 6;
    const int c = (tid < NB) ? bsum[tid] : 0;
    int v = c;
    #pragma unroll
    for (int off = 1; off < 64; off <<= 1) {
        const int t = __shfl_up(v, off);
        if (lane >= off) v += t;
    }
    if (lane == 63) wsum[wv] = v;
    __syncthreads();
    int add = 0;
    for (int w = 0; w < wv; ++w) add += wsum[w];
    if (tid < NB) bpre[tid] = add + v - c;
}

__global__ __launch_bounds__(256)
void scan3_kernel(int* __restrict__ offs, const int* __restrict__ bpre,
                  const int* __restrict__ countsA,
                  int* __restrict__ cursorA, int* __restrict__ cursorB,
                  int* __restrict__ mid)
{
    const int i = blockIdx.x * 256 + threadIdx.x;
    if (i < NROWS) {
        const int v = offs[i] + bpre[blockIdx.x];
        offs[i] = v;
        cursorA[i] = v;
        const int m = v + countsA[i];
        mid[i] = m;
        cursorB[i] = m;
    }
    if (i == 0) offs[NROWS] = 12 * NROWS;
}

__global__ __launch_bounds__(256)
void fill_kernel(const int* __restrict__ pidx, const int* __restrict__ sidx,
                 const int* __restrict__ nhp, const int* __restrict__ nhs,
                 const int* __restrict__ mrank,
                 int* __restrict__ cursorA, int* __restrict__ cursorB,
                 int* __restrict__ entries)
{
    const int i = blockIdx.x * 256 + threadIdx.x;
    if (i >= NROWS) return;
    const int s = blockIdx.y;
    const int k = s >> 1, dir = s & 1;
    const int* scp = (dir ? pidx : sidx) + k * NROWS;
    const int* gp  = (dir ? nhs  : nhp)  + k * NROWS;
    const int dst = scp[i];
    const int pos = (s < 6) ? atomicAdd(&cursorA[dst], 1)
                            : atomicAdd(&cursorB[dst], 1);
    entries[pos] = (s << 16) | mrank[(size_t)s * NROWS + gp[i]];
}

// ---------------------------------------------------------------------------
// combine over compacted slots (stride EMAXND).
// half=0 -> [offs, mid); half=1 -> [mid, offs+1); -1 -> all.
// ---------------------------------------------------------------------------
template<int FIRST, int LAST>
__global__ __launch_bounds__(256)
void combine_f16(const _Float16* __restrict__ YC, _Float16* __restrict__ TEMP16,
                 const _Float16* __restrict__ YB,
                 const int* __restrict__ offsets, const int* __restrict__ mid,
                 const int* __restrict__ entries,
                 int c0, int nch, int half,
                 const float* __restrict__ gw, const float* __restrict__ gb,
                 _Float16* __restrict__ Hh)
{
    const int lane = threadIdx.x & 63;
    const int wv   = threadIdx.x >> 6;
    const int r    = blockIdx.x * 4 + wv;
    if (r >= NROWS) return;
    const size_t rowoff = (size_t)r * DIM + lane * 4;

    const f16x4 ivv = FIRST ? *(const f16x4*)(YC + rowoff)
                            : *(const f16x4*)(TEMP16 + rowoff);
    float4 acc;
    acc.x = (float)ivv[0]; acc.y = (float)ivv[1];
    acc.z = (float)ivv[2]; acc.w = (float)ivv[3];

    int e0, e1;
    if (half == 0)      { e0 = offsets[r]; e1 = mid[r]; }
    else if (half == 1) { e0 = mid[r];     e1 = offsets[r + 1]; }
    else                { e0 = offsets[r]; e1 = offsets[r + 1]; }

    for (int e = e0; e < e1; ++e) {
        const int ent = entries[e];
        const int s = ent >> 16;
        if ((unsigned)(s - c0) < (unsigned)nch) {
            const f16x4 yv = *(const f16x4*)(YB + (size_t)(s - c0) * EMAXND
                                             + (size_t)(ent & 0xFFFF) * DIM + lane * 4);
            acc.x += (float)yv[0]; acc.y += (float)yv[1];
            acc.z += (float)yv[2]; acc.w += (float)yv[3];
        }
    }

    if (LAST) {
        float s  = acc.x + acc.y + acc.z + acc.w;
        float ss = acc.x * acc.x + acc.y * acc.y + acc.z * acc.z + acc.w * acc.w;
        #pragma unroll
        for (int off = 32; off >= 1; off >>= 1) {
            s  += __shfl_xor(s, off);
            ss += __shfl_xor(ss, off);
        }
        const float m   = s * (1.0f / DIM);
        const float var = ss * (1.0f / DIM) - m * m;
        const float inv = rsqrtf(var + EPSV);
        const float4 wv4 = *(const float4*)(gw + lane * 4);
        const float4 bv4 = *(const float4*)(gb + lane * 4);
        f16x4 o;
        o[0] = (_Float16)fmaxf((acc.x - m) * inv * wv4.x + bv4.x, 0.f);
        o[1] = (_Float16)fmaxf((acc.y - m) * inv * wv4.y + bv4.y, 0.f);
        o[2] = (_Float16)fmaxf((acc.z - m) * inv * wv4.z + bv4.z, 0.f);
        o[3] = (_Float16)fmaxf((acc.w - m) * inv * wv4.w + bv4.w, 0.f);
        *(f16x4*)(Hh + rowoff) = o;
    } else {
        f16x4 o;
        o[0] = (_Float16)acc.x; o[1] = (_Float16)acc.y;
        o[2] = (_Float16)acc.z; o[3] = (_Float16)acc.w;
        *(f16x4*)(TEMP16 + rowoff) = o;
    }
}

// ---------------------------------------------------------------------------
extern "C" void kernel_launch(void* const* d_in, const int* in_sizes, int n_in,
                              void* d_out, int out_size, void* d_ws, size_t ws_size,
                              hipStream_t stream)
{
    const float* lane   = (const float*)d_in[0];
    const float* W_ctr  = (const float*)d_in[1];
    const float* norm_w = (const float*)d_in[2];
    const float* norm_b = (const float*)d_in[3];
    const float* W_ctr2 = (const float*)d_in[4];
    const float* c2w    = (const float*)d_in[5];
    const float* c2b    = (const float*)d_in[6];
    const float* W_pre  = (const float*)d_in[7];
    const float* W_suc  = (const float*)d_in[8];
    const int*   pidx   = (const int*)d_in[9];
    const int*   sidx   = (const int*)d_in[10];
    const int*   nhp    = (const int*)d_in[11];
    const int*   nhs    = (const int*)d_in[12];

    float* X = (float*)d_out;

    // ---- workspace layout ----
    char* p = (char*)d_ws;
    int* counts  = (int*)p; p += (size_t)NROWS * 4;
    int* countsA = (int*)p; p += (size_t)NROWS * 4;
    int* offsets = (int*)p; p += (size_t)(NROWS + 4) * 4;
    int* mid     = (int*)p; p += (size_t)NROWS * 4;
    int* cursorA = (int*)p; p += (size_t)NROWS * 4;
    int* cursorB = (int*)p; p += (size_t)NROWS * 4;
    int* bsum    = (int*)p; p += 256 * 4;
    int* bpre    = (int*)p; p += 256 * 4;
    int* msum    = (int*)p; p += 12 * 256 * 4;
    int* mbpre   = (int*)p; p += 12 * 256 * 4;
    int* Ecnt    = (int*)p; p += 16 * 4;
    int* entries = (int*)p; p += (size_t)12 * NROWS * 4;
    int* LIVE    = (int*)p; p += (size_t)12 * NROWS * 4;
    p = (char*)(((uintptr_t)p + 15) & ~(uintptr_t)15);
    _Float16* Xh   = (_Float16*)p; p += ND * 2;
    _Float16* Hh   = (_Float16*)p; p += ND * 2;
    _Float16* T16  = (_Float16*)p; p += ND * 2;
    _Float16* WH   = (_Float16*)p; p += (size_t)56 * DIM * DIM * 2;
    p = (char*)(((uintptr_t)p + 15) & ~(uintptr_t)15);
    _Float16* YC   = (_Float16*)p; p += ND * 2;
    _Float16* YBUF = (_Float16*)p;            // compacted slots, stride EMAXND

    int* mark  = (int*)YBUF;                  // prep-only aliases
    int* mrank = mark + (size_t)12 * NROWS;

    const size_t used = (size_t)(p - (char*)d_ws);
    const size_t slotb = EMAXND * 2;
    int nslot = (ws_size > used) ? (int)((ws_size - used) / slotb) : 1;
    if (nslot < 1) nslot = 1;
    int CH;
    if (nslot >= 12) CH = 12;
    else {
        CH = nslot;
        const int nchunks = (12 + CH - 1) / CH;
        CH = (12 + nchunks - 1) / nchunks;
    }

    const dim3 blk(256);
    const int  gnBlocks = (NROWS + 3) / 4;
    const int  cwBlocks = (int)(((size_t)56 * DIM * DIM / 4 + 255) / 256);
    const int  ixBlocks = (int)((ND / 4 + 255) / 256);

    // one-time prep
    convert_w<<<cwBlocks, blk, 0, stream>>>(W_ctr, W_ctr2, W_pre, W_suc, WH);
    init_x<<<ixBlocks, blk, 0, stream>>>(lane, Xh);
    hipMemsetAsync(counts, 0, NROWS * sizeof(int), stream);
    hipMemsetAsync(countsA, 0, NROWS * sizeof(int), stream);
    hipMemsetAsync(mark, 0, (size_t)12 * NROWS * sizeof(int), stream);
    markk<<<dim3(NB, 12), blk, 0, stream>>>(nhp, nhs, mark);
    mscan1<<<dim3(NB, 12), blk, 0, stream>>>(mark, mrank, msum);
    mscan2<<<12, blk, 0, stream>>>(msum, mbpre, Ecnt);
    mscan3<<<dim3(NB, 12), blk, 0, stream>>>(mark, mrank, mbpre, LIVE);
    count_kernel<<<dim3(NB, 12), blk, 0, stream>>>(pidx, sidx, counts, countsA);
    scan1_kernel<<<NB, blk, 0, stream>>>(counts, offsets, bsum);
    scan2_kernel<<<1, blk, 0, stream>>>(bsum, bpre);
    scan3_kernel<<<NB, blk, 0, stream>>>(offsets, bpre, countsA,
                                         cursorA, cursorB, mid);
    fill_kernel<<<dim3(NB, 12), blk, 0, stream>>>(pidx, sidx, nhp, nhs, mrank,
                                                  cursorA, cursorB, entries);

    for (int i = 0; i < ROUNDS; ++i) {
        for (int c0 = 0; c0 < 12; c0 += CH) {
            const int nz = (12 - c0 < CH) ? (12 - c0) : CH;
            const bool first = (c0 == 0);
            const bool last  = (c0 + nz >= 12);
            const int ctr0  = first ? 1 : 0;
            const int slots = nz + ctr0;
            const int nwg   = 391 * 2 * slots;
            gemm_p<<<dim3(nwg), blk, 0, stream>>>(
                Xh, WH, first ? (48 + i) : (i * 12 + c0), i * 12 + c0 - ctr0,
                slots, YC, YBUF, ctr0, nwg, LIVE, Ecnt, c0 - ctr0);
            const int half = (CH == 6) ? (first ? 0 : 1) : -1;
            if (first && last)
                combine_f16<1, 1><<<gnBlocks, blk, 0, stream>>>(YC, T16, YBUF,
                    offsets, mid, entries, c0, nz, half,
                    norm_w + i * DIM, norm_b + i * DIM, Hh);
            else if (first)
                combine_f16<1, 0><<<gnBlocks, blk, 0, stream>>>(YC, T16, YBUF,
                    offsets, mid, entries, c0, nz, half,
                    norm_w + i * DIM, norm_b + i * DIM, Hh);
            else if (last)
                combine_f16<0, 1><<<gnBlocks, blk, 0, stream>>>(YC, T16, YBUF,
                    offsets, mid, entries, c0, nz, half,
                    norm_w + i * DIM, norm_b + i * DIM, Hh);
            else
                combine_f16<0, 0><<<gnBlocks, blk, 0, stream>>>(YC, T16, YBUF,
                    offsets, mid, entries, c0, nz, half,
                    norm_w + i * DIM, norm_b + i * DIM, Hh);
        }
        // x = relu(gn(Hh @ W_ctr2^T) + x), fused; X fp32 only in final round
        gemm_gn<<<391, 512, 0, stream>>>(Hh, WH, 52 + i, c2w + i * DIM,
                                         c2b + i * DIM, X, Xh,
                                         (i == ROUNDS - 1) ? 1 : 0);
    }
}

// Round 13
// 953.251 us; speedup vs baseline: 1.5556x; 1.1293x over previous
//
#include <hip/hip_runtime.h>

#define NROWS 50000
#define DIM   256
#define SHOPS 6
#define ROUNDS 4
#define EPSV  1e-5f
#define ND ((size_t)NROWS * DIM)
#define NB  196                              // ceil(NROWS/256)
#define EMAXR 32768                          // live rows = 31606 +- ~110 (10 sigma)
#define EMAXND ((size_t)EMAXR * DIM)

typedef _Float16 f16x8 __attribute__((ext_vector_type(8)));
typedef _Float16 f16x4 __attribute__((ext_vector_type(4)));
typedef float    f32x4 __attribute__((ext_vector_type(4)));

#define GLDS16(GP, LP) \
    __builtin_amdgcn_global_load_lds((const __attribute__((address_space(1))) unsigned*)(GP), \
                                     (__attribute__((address_space(3))) unsigned*)(LP), 16, 0, 0)

__device__ __forceinline__ int imin(int a, int b) { return a < b ? a : b; }

// ---------------------------------------------------------------------------
// Pipelined fp16 MFMA GEMM, A-side gather + compacted output (r11/r12
// structure: panel-spread XCD swizzle, 3-buf counted-vmcnt, 64B-row XOR
// swizzle, LDS-transposed epilogue). Slot z: weight wslot(z)= z==0 ? s0 : s1+z;
// seg = sbase+z (seg<0 -> identity rows, all NROWS, dest C0); compacted slots
// write CZ + (z-ctr0)*EMAXND.
// ---------------------------------------------------------------------------
__global__ __launch_bounds__(256)
void gemm_p(const _Float16* __restrict__ A, const _Float16* __restrict__ WH,
            int s0, int s1, int nz, _Float16* __restrict__ C0,
            _Float16* __restrict__ CZ, int ctr0, int nwg,
            const int* __restrict__ LIVE, const int* __restrict__ Ecnt,
            int sbase)
{
    __shared__ _Float16 lds[3][8192];        // 48KB
    char* ldsb = (char*)lds;

    const int bid = blockIdx.x;
    const int q   = nwg >> 3, r = nwg & 7;
    const int xcd = bid & 7,  ii = bid >> 3;
    const int g   = (xcd < r) ? xcd * (q + 1) + ii
                              : r * (q + 1) + (xcd - r) * q + ii;
    const int j   = g / (2 * nz);
    const int sub = g - j * 2 * nz;
    const int by  = sub & 1;
    const size_t z = sub >> 1;
    int xp, jj;
    if (j < 7 * 49) { xp = j / 49; jj = j % 49; }
    else            { xp = 7; jj = j - 7 * 49; }
    const int bx = jj * 8 + xp;

    const int seg = sbase + (int)z;
    const int En  = (seg >= 0) ? Ecnt[seg] : NROWS;
    const int bm0 = bx * 128;
    if (bm0 >= En) return;
    const int* lvp = (seg >= 0) ? LIVE + (size_t)seg * NROWS : nullptr;

    const int tid = threadIdx.x;
    const int l   = tid & 63;
    const int w   = tid >> 6;
    const int wm  = w & 1;
    const int wn  = w >> 1;
    const int bn0 = by * 128;
    const int lr  = l & 15;
    const int sl  = l >> 4;

    const int wslot = (z == 0) ? s0 : s1 + (int)z;
    const char* Ab = (const char*)A;
    const char* Wb = (const char*)(WH + (size_t)wslot * (DIM * DIM));

    int arow[2], slog[2], wrow[2];
    #pragma unroll
    for (int qq = 0; qq < 2; ++qq) {
        const int c   = (w * 2 + qq) * 64 + l;
        const int row = c >> 2;
        slog[qq] = (c & 3) ^ ((row >> 1) & 3);
        const int cl = imin(bm0 + row, En - 1);
        arow[qq] = lvp ? lvp[cl] : cl;
        wrow[qq] = bn0 + row;
    }

    f32x4 acc[4][4];
    #pragma unroll
    for (int mt = 0; mt < 4; ++mt)
        #pragma unroll
        for (int nt = 0; nt < 4; ++nt)
            acc[mt][nt] = (f32x4){0.f, 0.f, 0.f, 0.f};

    auto stage = [&](int step, int buf) {
        const int kt64 = step * 64;
        char* base = ldsb + buf * 16384;
        #pragma unroll
        for (int qq = 0; qq < 2; ++qq) {
            GLDS16(Ab + (size_t)arow[qq] * 512 + kt64 + slog[qq] * 16,
                   base + (w * 2 + qq) * 1024);
            GLDS16(Wb + (size_t)wrow[qq] * 512 + kt64 + slog[qq] * 16,
                   base + 8192 + (w * 2 + qq) * 1024);
        }
    };

    auto compute = [&](int buf) {
        const char* base = ldsb + buf * 16384;
        f16x8 af[4], bf[4];
        #pragma unroll
        for (int mt = 0; mt < 4; ++mt) {
            const int row = wm * 64 + mt * 16 + lr;
            af[mt] = *(const f16x8*)(base + row * 64 + ((sl ^ ((row >> 1) & 3)) << 4));
        }
        #pragma unroll
        for (int nt = 0; nt < 4; ++nt) {
            const int row = wn * 64 + nt * 16 + lr;
            bf[nt] = *(const f16x8*)(base + 8192 + row * 64 + ((sl ^ ((row >> 1) & 3)) << 4));
        }
        #pragma unroll
        for (int mt = 0; mt < 4; ++mt)
            #pragma unroll
            for (int nt = 0; nt < 4; ++nt)
                acc[mt][nt] = __builtin_amdgcn_mfma_f32_16x16x32_f16(
                    af[mt], bf[nt], acc[mt][nt], 0, 0, 0);
    };

    stage(0, 0);
    stage(1, 1);
    #pragma unroll
    for (int t = 0; t < 7; ++t) {
        asm volatile("s_waitcnt vmcnt(4)" ::: "memory");
        __builtin_amdgcn_s_barrier();
        __builtin_amdgcn_sched_barrier(0);
        if (t < 6) stage(t + 2, (t + 2) % 3);
        compute(t % 3);
    }
    asm volatile("s_waitcnt vmcnt(0)" ::: "memory");
    __builtin_amdgcn_s_barrier();
    __builtin_amdgcn_sched_barrier(0);
    compute(7 % 3);

    __syncthreads();
    _Float16* et = (_Float16*)ldsb;           // [128][136]
    #pragma unroll
    for (int mt = 0; mt < 4; ++mt)
        #pragma unroll
        for (int nt = 0; nt < 4; ++nt)
            #pragma unroll
            for (int jv = 0; jv < 4; ++jv) {
                const int row = wm * 64 + mt * 16 + sl * 4 + jv;
                const int col = wn * 64 + nt * 16 + lr;
                et[row * 136 + col] = (_Float16)acc[mt][nt][jv];
            }
    __syncthreads();
    _Float16* Cb = (ctr0 && z == 0) ? C0 : CZ + (size_t)((int)z - ctr0) * EMAXND;
    #pragma unroll
    for (int qq = 0; qq < 8; ++qq) {
        const int c   = qq * 256 + tid;
        const int row = c >> 4;
        const int cc  = (c & 15) * 8;
        const int orow = bm0 + row;
        if (orow < En) {
            const f16x8 v = *(const f16x8*)(et + row * 136 + cc);
            *(f16x8*)(Cb + (size_t)orow * DIM + bn0 + cc) = v;
        }
    }
}

// ---------------------------------------------------------------------------
// Fused ctr2 GEMM + GroupNorm + residual + ReLU. 512 thr, tile 128x256.
// NOW 3-buffer counted-vmcnt pipeline (grid=391 -> LDS growth costs nothing).
// ---------------------------------------------------------------------------
__global__ __launch_bounds__(512)
void gemm_gn(const _Float16* __restrict__ A, const _Float16* __restrict__ WH,
             int wslot, const float* __restrict__ gw, const float* __restrict__ gb,
             float* __restrict__ X, _Float16* __restrict__ Xh, int writex)
{
    __shared__ char ldsb[3 * 24576 + 4096];   // 76.0 KB
    float* sArr  = (float*)(ldsb + 73728);    // [4][128]
    float* ssArr = sArr + 512;

    const int tid = threadIdx.x;
    const int l   = tid & 63;
    const int w   = tid >> 6;                 // 0..7
    const int wm  = w & 1;
    const int wn  = w >> 1;                   // 0..3
    const int bm0 = blockIdx.x * 128;
    const int lr  = l & 15;
    const int sl  = l >> 4;

    const char* Ab = (const char*)A;
    const char* Wb = (const char*)(WH + (size_t)wslot * (DIM * DIM));

    int arow, aslog, wr0, ws0, wr1, ws1;
    {
        int c = tid, row = c >> 2;
        aslog = (c & 3) ^ ((row >> 1) & 3);
        arow  = imin(bm0 + row, NROWS - 1);
        ws0 = aslog; wr0 = row;
        c = tid + 512; row = c >> 2;
        ws1 = (c & 3) ^ ((row >> 1) & 3); wr1 = row;
    }

    f32x4 acc[4][4];
    #pragma unroll
    for (int mt = 0; mt < 4; ++mt)
        #pragma unroll
        for (int nt = 0; nt < 4; ++nt)
            acc[mt][nt] = (f32x4){0.f, 0.f, 0.f, 0.f};

    auto stage = [&](int step, int buf) {
        const int kt64 = step * 64;
        char* base = ldsb + buf * 24576;
        GLDS16(Ab + (size_t)arow * 512 + kt64 + aslog * 16, base + w * 1024);
        GLDS16(Wb + (size_t)wr0 * 512 + kt64 + ws0 * 16, base + 8192 + w * 1024);
        GLDS16(Wb + (size_t)wr1 * 512 + kt64 + ws1 * 16, base + 16384 + w * 1024);
    };

    auto compute = [&](int buf) {
        const char* base = ldsb + buf * 24576;
        f16x8 af[4], bf[4];
        #pragma unroll
        for (int mt = 0; mt < 4; ++mt) {
            const int row = wm * 64 + mt * 16 + lr;
            af[mt] = *(const f16x8*)(base + row * 64 + ((sl ^ ((row >> 1) & 3)) << 4));
        }
        #pragma unroll
        for (int nt = 0; nt < 4; ++nt) {
            const int row = wn * 64 + nt * 16 + lr;
            bf[nt] = *(const f16x8*)(base + 8192 + row * 64 + ((sl ^ ((row >> 1) & 3)) << 4));
        }
        #pragma unroll
        for (int mt = 0; mt < 4; ++mt)
            #pragma unroll
            for (int nt = 0; nt < 4; ++nt)
                acc[mt][nt] = __builtin_amdgcn_mfma_f32_16x16x32_f16(
                    af[mt], bf[nt], acc[mt][nt], 0, 0, 0);
    };

    stage(0, 0);
    stage(1, 1);
    #pragma unroll
    for (int t = 0; t < 7; ++t) {
        asm volatile("s_waitcnt vmcnt(3)" ::: "memory");   // stage(t)'s 3 landed
        __builtin_amdgcn_s_barrier();
        __builtin_amdgcn_sched_barrier(0);
        if (t < 6) stage(t + 2, (t + 2) % 3);
        compute(t % 3);
    }
    asm volatile("s_waitcnt vmcnt(0)" ::: "memory");
    __builtin_amdgcn_s_barrier();
    __builtin_amdgcn_sched_barrier(0);
    compute(7 % 3);

    // ---- GN stats ----
    float sp[4][4], ssp[4][4];
    #pragma unroll
    for (int mt = 0; mt < 4; ++mt)
        #pragma unroll
        for (int jv = 0; jv < 4; ++jv) {
            float s = 0.f, ss = 0.f;
            #pragma unroll
            for (int nt = 0; nt < 4; ++nt) {
                const float v = acc[mt][nt][jv];
                s += v; ss += v * v;
            }
            sp[mt][jv] = s; ssp[mt][jv] = ss;
        }
    #pragma unroll
    for (int off = 1; off < 16; off <<= 1)
        #pragma unroll
        for (int mt = 0; mt < 4; ++mt)
            #pragma unroll
            for (int jv = 0; jv < 4; ++jv) {
                sp[mt][jv]  += __shfl_xor(sp[mt][jv], off);
                ssp[mt][jv] += __shfl_xor(ssp[mt][jv], off);
            }
    __syncthreads();
    if (lr == 0) {
        #pragma unroll
        for (int mt = 0; mt < 4; ++mt)
            #pragma unroll
            for (int jv = 0; jv < 4; ++jv) {
                const int row = wm * 64 + mt * 16 + sl * 4 + jv;
                sArr[wn * 128 + row]  = sp[mt][jv];
                ssArr[wn * 128 + row] = ssp[mt][jv];
            }
    }
    __syncthreads();
    float mv[4][4], iv[4][4];
    #pragma unroll
    for (int mt = 0; mt < 4; ++mt)
        #pragma unroll
        for (int jv = 0; jv < 4; ++jv) {
            const int row = wm * 64 + mt * 16 + sl * 4 + jv;
            const float S  = sArr[row] + sArr[128 + row] + sArr[256 + row] + sArr[384 + row];
            const float SS = ssArr[row] + ssArr[128 + row] + ssArr[256 + row] + ssArr[384 + row];
            const float m  = S * (1.0f / DIM);
            mv[mt][jv] = m;
            iv[mt][jv] = rsqrtf(SS * (1.0f / DIM) - m * m + EPSV);
        }
    float gwv[4], gbv[4];
    #pragma unroll
    for (int nt = 0; nt < 4; ++nt) {
        const int col = wn * 64 + nt * 16 + lr;
        gwv[nt] = gw[col]; gbv[nt] = gb[col];
    }

    _Float16* et = (_Float16*)ldsb;           // [64][264]
    #pragma unroll
    for (int half = 0; half < 2; ++half) {
        __syncthreads();
        if (wm == half) {
            #pragma unroll
            for (int mt = 0; mt < 4; ++mt)
                #pragma unroll
                for (int nt = 0; nt < 4; ++nt)
                    #pragma unroll
                    for (int jv = 0; jv < 4; ++jv) {
                        const int rl  = mt * 16 + sl * 4 + jv;
                        const int col = wn * 64 + nt * 16 + lr;
                        et[rl * 264 + col] = (_Float16)((acc[mt][nt][jv] - mv[mt][jv])
                                                        * iv[mt][jv] * gwv[nt] + gbv[nt]);
                    }
        }
        __syncthreads();
        #pragma unroll
        for (int qq = 0; qq < 4; ++qq) {
            const int c   = qq * 512 + tid;
            const int row = c >> 5;
            const int cc  = (c & 31) * 8;
            const int orow = bm0 + half * 64 + row;
            if (orow < NROWS) {
                const f16x8 y = *(const f16x8*)(et + row * 264 + cc);
                const f16x8 rr = *(const f16x8*)(Xh + (size_t)orow * DIM + cc);
                float o[8];
                #pragma unroll
                for (int e = 0; e < 8; ++e)
                    o[e] = fmaxf((float)y[e] + (float)rr[e], 0.f);
                f16x8 oh;
                #pragma unroll
                for (int e = 0; e < 8; ++e) oh[e] = (_Float16)o[e];
                *(f16x8*)(Xh + (size_t)orow * DIM + cc) = oh;
                if (writex) {
                    float* xp = X + (size_t)orow * DIM + cc;
                    *(float4*)xp       = make_float4(o[0], o[1], o[2], o[3]);
                    *(float4*)(xp + 4) = make_float4(o[4], o[5], o[6], o[7]);
                }
            }
        }
    }
}

// ---------------------------------------------------------------------------
// Fused prep kernels
// ---------------------------------------------------------------------------
// init_x (blocks 0..12499) + convert_w (blocks 12500..16083)
__global__ __launch_bounds__(256)
void cvt_init(const float* __restrict__ lane, _Float16* __restrict__ Xh,
              const float* __restrict__ Wctr, const float* __restrict__ Wctr2,
              const float* __restrict__ Wpre, const float* __restrict__ Wsuc,
              _Float16* __restrict__ WH)
{
    const int bid = blockIdx.x;
    if (bid < 12500) {
        const size_t i4 = (size_t)bid * 256 + threadIdx.x;
        if (i4 >= ND / 4) return;
        const float4 v = *(const float4*)(lane + i4 * 4);
        f16x4 h;
        h[0] = (_Float16)v.x; h[1] = (_Float16)v.y;
        h[2] = (_Float16)v.z; h[3] = (_Float16)v.w;
        *(f16x4*)(Xh + i4 * 4) = h;
    } else {
        const size_t i4 = (size_t)(bid - 12500) * 256 + threadIdx.x;
        const size_t NT = (size_t)56 * DIM * DIM / 4;
        if (i4 >= NT) return;
        const size_t e = i4 * 4;
        const int slot = (int)(e >> 16);
        const int off  = (int)(e & 65535);
        const float* src;
        if (slot < 48) {
            const int r = slot / 12, s = slot % 12, k = s >> 1, dir = s & 1;
            src = (dir ? Wsuc : Wpre) + (((size_t)r * SHOPS + k) << 16) + off;
        } else if (slot < 52) {
            src = Wctr + ((size_t)(slot - 48) << 16) + off;
        } else {
            src = Wctr2 + ((size_t)(slot - 52) << 16) + off;
        }
        const float4 v = *(const float4*)src;
        f16x4 h;
        h[0] = (_Float16)v.x; h[1] = (_Float16)v.y;
        h[2] = (_Float16)v.z; h[3] = (_Float16)v.w;
        *(f16x4*)(WH + e) = h;
    }
}

// markk + count fused
__global__ __launch_bounds__(256)
void markcount(const int* __restrict__ pidx, const int* __restrict__ sidx,
               const int* __restrict__ nhp, const int* __restrict__ nhs,
               int* __restrict__ mark, int* __restrict__ counts,
               int* __restrict__ countsA)
{
    const int i = blockIdx.x * 256 + threadIdx.x;
    if (i >= NROWS) return;
    const int s = blockIdx.y;
    const int k = s >> 1, dir = s & 1;
    const int* gp  = (dir ? nhs  : nhp)  + k * NROWS;
    const int* scp = (dir ? pidx : sidx) + k * NROWS;
    mark[(size_t)s * NROWS + gp[i]] = 1;
    const int dst = scp[i];
    atomicAdd(&counts[dst], 1);
    if (s < 6) atomicAdd(&countsA[dst], 1);
}

// pass 1 scans: y<12 -> mark seg y; y==12 -> counts
__global__ __launch_bounds__(256)
void pscan1(const int* __restrict__ mark, const int* __restrict__ counts,
            int* __restrict__ mrank, int* __restrict__ msum,
            int* __restrict__ offs, int* __restrict__ bsum)
{
    __shared__ int wsum[4];
    const int y = blockIdx.y;
    const int tid = threadIdx.x, lane = tid & 63, wv = tid >> 6;
    const int i = blockIdx.x * 256 + tid;
    const int c = (i < NROWS) ? ((y < 12) ? mark[(size_t)y * NROWS + i] : counts[i]) : 0;
    int v = c;
    #pragma unroll
    for (int off = 1; off < 64; off <<= 1) {
        const int t = __shfl_up(v, off);
        if (lane >= off) v += t;
    }
    if (lane == 63) wsum[wv] = v;
    __syncthreads();
    int add = 0;
    for (int w = 0; w < wv; ++w) add += wsum[w];
    const int excl = add + v - c;
    if (i < NROWS) {
        if (y < 12) mrank[(size_t)y * NROWS + i] = excl;
        else        offs[i] = excl;
    }
    if (tid == 255) {
        const int tot = wsum[0] + wsum[1] + wsum[2] + wsum[3];
        if (y < 12) msum[y * 256 + blockIdx.x] = tot;
        else        bsum[blockIdx.x] = tot;
    }
}

// pass 2 scans: x<12 -> msum seg x (+Ecnt); x==12 -> bsum
__global__ __launch_bounds__(256)
void pscan2(const int* __restrict__ msum, const int* __restrict__ bsum,
            int* __restrict__ mbpre, int* __restrict__ bpre,
            int* __restrict__ Ecnt)
{
    __shared__ int wsum[4];
    const int y = blockIdx.x;
    const int tid = threadIdx.x, lane = tid & 63, wv = tid >> 6;
    const int c = (tid < NB) ? ((y < 12) ? msum[y * 256 + tid] : bsum[tid]) : 0;
    int v = c;
    #pragma unroll
    for (int off = 1; off < 64; off <<= 1) {
        const int t = __shfl_up(v, off);
        if (lane >= off) v += t;
    }
    if (lane == 63) wsum[wv] = v;
    __syncthreads();
    int add = 0;
    for (int w = 0; w < wv; ++w) add += wsum[w];
    if (tid < NB) {
        if (y < 12) mbpre[y * 256 + tid] = add + v - c;
        else        bpre[tid] = add + v - c;
    }
    if (tid == 0 && y < 12)
        Ecnt[y] = wsum[0] + wsum[1] + wsum[2] + wsum[3];
}

// pass 3: y<12 -> finalize mrank + build LIVE; y==12 -> finalize offs/cursors/mid
__global__ __launch_bounds__(256)
void pscan3(const int* __restrict__ mark, int* __restrict__ mrank,
            const int* __restrict__ mbpre, int* __restrict__ live,
            int* __restrict__ offs, const int* __restrict__ bpre,
            const int* __restrict__ countsA, int* __restrict__ cursorA,
            int* __restrict__ cursorB, int* __restrict__ mid)
{
    const int i = blockIdx.x * 256 + threadIdx.x;
    const int y = blockIdx.y;
    if (y < 12) {
        if (i >= NROWS) return;
        const size_t o = (size_t)y * NROWS + i;
        const int rk = mrank[o] + mbpre[y * 256 + blockIdx.x];
        mrank[o] = rk;
        if (mark[o]) live[(size_t)y * NROWS + rk] = i;
    } else {
        if (i < NROWS) {
            const int v = offs[i] + bpre[blockIdx.x];
            offs[i] = v;
            cursorA[i] = v;
            const int m = v + countsA[i];
            mid[i] = m;
            cursorB[i] = m;
        }
        if (i == 0) offs[NROWS] = 12 * NROWS;
    }
}

__global__ __launch_bounds__(256)
void fill_kernel(const int* __restrict__ pidx, const int* __restrict__ sidx,
                 const int* __restrict__ nhp, const int* __restrict__ nhs,
                 const int* __restrict__ mrank,
                 int* __restrict__ cursorA, int* __restrict__ cursorB,
                 int* __restrict__ entries)
{
    const int i = blockIdx.x * 256 + threadIdx.x;
    if (i >= NROWS) return;
    const int s = blockIdx.y;
    const int k = s >> 1, dir = s & 1;
    const int* scp = (dir ? pidx : sidx) + k * NROWS;
    const int* gp  = (dir ? nhs  : nhp)  + k * NROWS;
    const int dst = scp[i];
    const int pos = (s < 6) ? atomicAdd(&cursorA[dst], 1)
                            : atomicAdd(&cursorB[dst], 1);
    entries[pos] = (s << 16) | mrank[(size_t)s * NROWS + gp[i]];
}

// ---------------------------------------------------------------------------
// combine: prefetch-pipelined gather over compacted slots (stride EMAXND).
// half=0 -> [offs,mid); half=1 -> [mid,offs+1); -1 -> all. No seg filter:
// host guarantees CH in {6,12} so half-ranges exactly match chunks.
// ---------------------------------------------------------------------------
#define PF 20
template<int FIRST, int LAST>
__global__ __launch_bounds__(256)
void combine_f16(const _Float16* __restrict__ YC, _Float16* __restrict__ TEMP16,
                 const _Float16* __restrict__ YB,
                 const int* __restrict__ offsets, const int* __restrict__ mid,
                 const int* __restrict__ entries,
                 int c0, int half,
                 const float* __restrict__ gw, const float* __restrict__ gb,
                 _Float16* __restrict__ Hh)
{
    const int lane = threadIdx.x & 63;
    const int wv   = threadIdx.x >> 6;
    const int r    = blockIdx.x * 4 + wv;
    if (r >= NROWS) return;
    const size_t rowoff = (size_t)r * DIM + lane * 4;

    const f16x4 ivv = FIRST ? *(const f16x4*)(YC + rowoff)
                            : *(const f16x4*)(TEMP16 + rowoff);
    float4 acc;
    acc.x = (float)ivv[0]; acc.y = (float)ivv[1];
    acc.z = (float)ivv[2]; acc.w = (float)ivv[3];

    int e0, e1;
    if (half == 0)      { e0 = offsets[r]; e1 = mid[r]; }
    else if (half == 1) { e0 = mid[r];     e1 = offsets[r + 1]; }
    else                { e0 = offsets[r]; e1 = offsets[r + 1]; }

    const int n  = e1 - e0;
    const int nf = n < PF ? n : PF;
    f16x4 buf[PF];
    #pragma unroll
    for (int t = 0; t < PF; ++t) {
        if (t < nf) {
            const int ent = entries[e0 + t];
            buf[t] = *(const f16x4*)(YB + (size_t)((ent >> 16) - c0) * EMAXND
                                     + (size_t)(ent & 0xFFFF) * DIM + lane * 4);
        }
    }
    #pragma unroll
    for (int t = 0; t < PF; ++t) {
        if (t < nf) {
            acc.x += (float)buf[t][0]; acc.y += (float)buf[t][1];
            acc.z += (float)buf[t][2]; acc.w += (float)buf[t][3];
        }
    }
    for (int e = e0 + nf; e < e1; ++e) {
        const int ent = entries[e];
        const f16x4 yv = *(const f16x4*)(YB + (size_t)((ent >> 16) - c0) * EMAXND
                                         + (size_t)(ent & 0xFFFF) * DIM + lane * 4);
        acc.x += (float)yv[0]; acc.y += (float)yv[1];
        acc.z += (float)yv[2]; acc.w += (float)yv[3];
    }

    if (LAST) {
        float s  = acc.x + acc.y + acc.z + acc.w;
        float ss = acc.x * acc.x + acc.y * acc.y + acc.z * acc.z + acc.w * acc.w;
        #pragma unroll
        for (int off = 32; off >= 1; off >>= 1) {
            s  += __shfl_xor(s, off);
            ss += __shfl_xor(ss, off);
        }
        const float m   = s * (1.0f / DIM);
        const float var = ss * (1.0f / DIM) - m * m;
        const float inv = rsqrtf(var + EPSV);
        const float4 wv4 = *(const float4*)(gw + lane * 4);
        const float4 bv4 = *(const float4*)(gb + lane * 4);
        f16x4 o;
        o[0] = (_Float16)fmaxf((acc.x - m) * inv * wv4.x + bv4.x, 0.f);
        o[1] = (_Float16)fmaxf((acc.y - m) * inv * wv4.y + bv4.y, 0.f);
        o[2] = (_Float16)fmaxf((acc.z - m) * inv * wv4.z + bv4.z, 0.f);
        o[3] = (_Float16)fmaxf((acc.w - m) * inv * wv4.w + bv4.w, 0.f);
        *(f16x4*)(Hh + rowoff) = o;
    } else {
        f16x4 o;
        o[0] = (_Float16)acc.x; o[1] = (_Float16)acc.y;
        o[2] = (_Float16)acc.z; o[3] = (_Float16)acc.w;
        *(f16x4*)(TEMP16 + rowoff) = o;
    }
}

// ---------------------------------------------------------------------------
extern "C" void kernel_launch(void* const* d_in, const int* in_sizes, int n_in,
                              void* d_out, int out_size, void* d_ws, size_t ws_size,
                              hipStream_t stream)
{
    const float* lane   = (const float*)d_in[0];
    const float* W_ctr  = (const float*)d_in[1];
    const float* norm_w = (const float*)d_in[2];
    const float* norm_b = (const float*)d_in[3];
    const float* W_ctr2 = (const float*)d_in[4];
    const float* c2w    = (const float*)d_in[5];
    const float* c2b    = (const float*)d_in[6];
    const float* W_pre  = (const float*)d_in[7];
    const float* W_suc  = (const float*)d_in[8];
    const int*   pidx   = (const int*)d_in[9];
    const int*   sidx   = (const int*)d_in[10];
    const int*   nhp    = (const int*)d_in[11];
    const int*   nhs    = (const int*)d_in[12];

    float* X = (float*)d_out;
    _Float16* YC = (_Float16*)d_out;          // ctr slot lives in d_out (25.6MB of 51.2)

    // ---- workspace layout ----
    char* p = (char*)d_ws;
    int* counts  = (int*)p; p += (size_t)NROWS * 4;
    int* countsA = (int*)p; p += (size_t)NROWS * 4;   // adjacent: single memset
    int* offsets = (int*)p; p += (size_t)(NROWS + 4) * 4;
    int* mid     = (int*)p; p += (size_t)NROWS * 4;
    int* cursorA = (int*)p; p += (size_t)NROWS * 4;
    int* cursorB = (int*)p; p += (size_t)NROWS * 4;
    int* bsum    = (int*)p; p += 256 * 4;
    int* bpre    = (int*)p; p += 256 * 4;
    int* msum    = (int*)p; p += 12 * 256 * 4;
    int* mbpre   = (int*)p; p += 12 * 256 * 4;
    int* Ecnt    = (int*)p; p += 16 * 4;
    int* entries = (int*)p; p += (size_t)12 * NROWS * 4;
    int* LIVE    = (int*)p; p += (size_t)12 * NROWS * 4;
    p = (char*)(((uintptr_t)p + 15) & ~(uintptr_t)15);
    _Float16* Xh = (_Float16*)p; p += ND * 2;
    _Float16* Hh = (_Float16*)p; p += ND * 2;
    _Float16* WH = (_Float16*)p; p += (size_t)56 * DIM * DIM * 2;
    p = (char*)(((uintptr_t)p + 255) & ~(uintptr_t)255);
    char* area = p;

    const size_t areaB = ws_size - (size_t)(area - (char*)d_ws);
    const size_t slotb = EMAXND * 2;          // 16.78 MB
    int CH;
    _Float16 *T16, *YBUF;
    if (areaB >= 12 * slotb) {                // single-chunk mode (needs ~201MB)
        CH = 12;
        YBUF = (_Float16*)area;
        T16 = Hh;                             // unused in this mode
    } else {                                  // proven CH=6 fallback
        CH = 6;
        T16 = (_Float16*)area;
        YBUF = T16 + ND;
    }

    int* mark  = (int*)area;                  // prep-only aliases (pre-GEMM)
    int* mrank = mark + (size_t)12 * NROWS;

    const dim3 blk(256);
    const int  gnBlocks = (NROWS + 3) / 4;

    // one-time prep (fused)
    cvt_init<<<16084, blk, 0, stream>>>(lane, Xh, W_ctr, W_ctr2, W_pre, W_suc, WH);
    hipMemsetAsync(counts, 0, 2 * NROWS * sizeof(int), stream);
    hipMemsetAsync(mark, 0, (size_t)12 * NROWS * sizeof(int), stream);
    markcount<<<dim3(NB, 12), blk, 0, stream>>>(pidx, sidx, nhp, nhs,
                                                mark, counts, countsA);
    pscan1<<<dim3(NB, 13), blk, 0, stream>>>(mark, counts, mrank, msum, offsets, bsum);
    pscan2<<<13, blk, 0, stream>>>(msum, bsum, mbpre, bpre, Ecnt);
    pscan3<<<dim3(NB, 13), blk, 0, stream>>>(mark, mrank, mbpre, LIVE,
                                             offsets, bpre, countsA,
                                             cursorA, cursorB, mid);
    fill_kernel<<<dim3(NB, 12), blk, 0, stream>>>(pidx, sidx, nhp, nhs, mrank,
                                                  cursorA, cursorB, entries);

    for (int i = 0; i < ROUNDS; ++i) {
        if (CH == 12) {
            // one GEMM: z=0 ctr -> YC; z=1..12 msg segs 0..11 -> YBUF slots
            const int nwg = 391 * 2 * 13;
            gemm_p<<<dim3(nwg), blk, 0, stream>>>(Xh, WH, 48 + i, i * 12 - 1,
                                                  13, YC, YBUF, 1, nwg,
                                                  LIVE, Ecnt, -1);
            combine_f16<1, 1><<<gnBlocks, blk, 0, stream>>>(YC, T16, YBUF,
                offsets, mid, entries, 0, -1,
                norm_w + i * DIM, norm_b + i * DIM, Hh);
        } else {
            for (int c0 = 0; c0 < 12; c0 += 6) {
                const bool first = (c0 == 0);
                const int ctr0  = first ? 1 : 0;
                const int slots = 6 + ctr0;
                const int nwg   = 391 * 2 * slots;
                gemm_p<<<dim3(nwg), blk, 0, stream>>>(
                    Xh, WH, first ? (48 + i) : (i * 12 + c0), i * 12 + c0 - ctr0,
                    slots, YC, YBUF, ctr0, nwg, LIVE, Ecnt, c0 - ctr0);
                if (first)
                    combine_f16<1, 0><<<gnBlocks, blk, 0, stream>>>(YC, T16, YBUF,
                        offsets, mid, entries, c0, 0,
                        norm_w + i * DIM, norm_b + i * DIM, Hh);
                else
                    combine_f16<0, 1><<<gnBlocks, blk, 0, stream>>>(YC, T16, YBUF,
                        offsets, mid, entries, c0, 1,
                        norm_w + i * DIM, norm_b + i * DIM, Hh);
            }
        }
        // x = relu(gn(Hh @ W_ctr2^T) + x); X fp32 only in final round
        gemm_gn<<<391, 512, 0, stream>>>(Hh, WH, 52 + i, c2w + i * DIM,
                                         c2b + i * DIM, X, Xh,
                                         (i == ROUNDS - 1) ? 1 : 0);
    }
}